// Round 12
// baseline (250.235 us; speedup 1.0000x reference)
//
#include <hip/hip_runtime.h>
#include <math.h>

typedef __bf16 bf16_t;
typedef __bf16 bf16x8 __attribute__((ext_vector_type(8)));
typedef __bf16 bf16x4 __attribute__((ext_vector_type(4)));
typedef float  f32x4  __attribute__((ext_vector_type(4)));
typedef _Float16 f16_t;
typedef _Float16 f16x4 __attribute__((ext_vector_type(4)));
typedef _Float16 f16x8 __attribute__((ext_vector_type(8)));
typedef __fp16 hf16x2 __attribute__((ext_vector_type(2)));

static constexpr float ATT_SCALE = 0.15811388300841897f; // 40^-0.5
static constexpr float SC2 = 0.22811031f;                // ATT_SCALE * log2(e)
static constexpr float LOG2E = 1.4426950408889634f;

__device__ __forceinline__ bf16_t f2b(float f) {
  unsigned u = __float_as_uint(f);
  u = (u + 0x7fffu + ((u >> 16) & 1u)) >> 16;   // RNE
  unsigned short s = (unsigned short)u;
  bf16_t r;
  *(unsigned short*)&r = s;
  return r;
}
__device__ __forceinline__ float b2f(bf16_t b) {
  unsigned short s = *(const unsigned short*)&b;
  return __uint_as_float(((unsigned)s) << 16);
}
__device__ __forceinline__ void sto(float v, float* p)  { *p = v; }
__device__ __forceinline__ void sto(float v, bf16_t* p) { *p = f2b(v); }
__device__ __forceinline__ unsigned pkh2(float a, float b) {
  hf16x2 h = __builtin_amdgcn_cvt_pkrtz(a, b);
  return *(unsigned*)&h;
}
// Direct global->LDS DMA, 16B per lane. lptr must be WAVE-UNIFORM; HW scatters lane i
// to lptr + i*16. Global address is per-lane (enables source-side swizzle, guide rule #21).
__device__ __forceinline__ void gl_lds16(const void* g, void* l) {
  __builtin_amdgcn_global_load_lds((const __attribute__((address_space(1))) unsigned*)g,
                                   (__attribute__((address_space(3))) unsigned*)l, 16, 0, 0);
}

// =========================== fused weight repack + LN1 (launch-merge) ===========================
__global__ __launch_bounds__(256) void prep_ln_kernel(
    const float* __restrict__ Wq1, const float* __restrict__ Wk1, const float* __restrict__ Wv1,
    const float* __restrict__ Wo1, const float* __restrict__ Wq2,
    const float* __restrict__ Wk2, const float* __restrict__ Wv2, const float* __restrict__ Wo2,
    const float* __restrict__ Wff1, const float* __restrict__ Wff2,
    const float* __restrict__ fam,
    bf16_t* __restrict__ wqkvt, bf16_t* __restrict__ wo1t, float* __restrict__ wkv2t,
    bf16_t* __restrict__ wo2t, bf16_t* __restrict__ wff1t, bf16_t* __restrict__ wff2t,
    bf16_t* __restrict__ wq2th, bf16_t* __restrict__ wq2tl,
    bf16_t* __restrict__ famh, bf16_t* __restrict__ faml,
    bf16_t* __restrict__ zpad,
    const float* __restrict__ x, const float* __restrict__ g1, const float* __restrict__ b1,
    bf16_t* __restrict__ h1b)
{
  const int b = blockIdx.x;
  const int tid = threadIdx.x;

  if (b >= 634) {   // ---- LN1 path ----
    const int bb = b - 634;
    const int lane = tid & 63;
    const int row = bb * 4 + (tid >> 6);
    const float* xr = x + (size_t)row * 320;
    float v[5], s = 0.f, s2 = 0.f;
#pragma unroll
    for (int i = 0; i < 5; i++) { v[i] = xr[lane + i*64]; s += v[i]; s2 += v[i]*v[i]; }
#pragma unroll
    for (int o = 32; o; o >>= 1) { s += __shfl_xor(s, o); s2 += __shfl_xor(s2, o); }
    float mu = s * (1.f/320.f);
    float rs = rsqrtf(fmaxf(s2*(1.f/320.f) - mu*mu, 0.f) + 1e-5f);
#pragma unroll
    for (int i = 0; i < 5; i++) {
      int c = lane + i*64;
      h1b[(size_t)row*320 + c] = f2b((v[i]-mu)*rs*g1[c] + b1[c]);
    }
    return;
  }

  if (b >= 570) {   // ---- elementwise tail: fam (9216) + zpad (135168) ----
    for (int idx = (b - 570)*256 + tid; idx < 9216 + 135168; idx += 64*256) {
      if (idx < 9216) {
        int d = idx / 96, k = idx - d*96;
        float v = (d < 77 && k < 77) ? fam[d*77 + k] : 0.f;
        bf16_t h = f2b(v);
        famh[idx] = h;
        faml[idx] = f2b(v - b2f(h));
      } else {
        zpad[idx - 9216] = f2b(0.f);
      }
    }
    return;
  }

  // ---- tile transpose path ----
  __shared__ float T[64][65];
  const float* src; int S, O, n0, k0, mode;   // mode: 0=bf16, 1=f32, 2=dual hi/lo
  float scale = 1.f;
  bf16_t* outb = nullptr; float* outf = nullptr;
  int nadj;

  if (b < 75) {            // wqkvt [960][320] <- {Wq1*SC2, Wk1, Wv1}[320][320]
    int tn = b / 5, tk = b - tn*5;
    n0 = tn*64; k0 = tk*64; S = 320; O = 320; mode = 0; outb = wqkvt;
    if (n0 < 320)      { src = Wq1; nadj = n0;       scale = SC2; }
    else if (n0 < 640) { src = Wk1; nadj = n0 - 320; }
    else               { src = Wv1; nadj = n0 - 640; }
  } else if (b < 100) {    // wo1t [320][320] <- Wo1
    int b2 = b - 75; int tn = b2 / 5, tk = b2 - tn*5;
    n0 = tn*64; k0 = tk*64; S = 320; O = 320; mode = 0; outb = wo1t; src = Wo1; nadj = n0;
  } else if (b < 220) {    // wkv2t f32 [640][768] <- {Wk2, Wv2}[768][320]
    int b2 = b - 100; int tn = b2 / 12, tk = b2 - tn*12;
    n0 = tn*64; k0 = tk*64; S = 320; O = 768; mode = 1; outf = wkv2t;
    if (n0 < 320) { src = Wk2; nadj = n0; } else { src = Wv2; nadj = n0 - 320; }
  } else if (b < 245) {    // wo2t [320][320] <- Wo2
    int b2 = b - 220; int tn = b2 / 5, tk = b2 - tn*5;
    n0 = tn*64; k0 = tk*64; S = 320; O = 320; mode = 0; outb = wo2t; src = Wo2; nadj = n0;
  } else if (b < 445) {    // wff1t [2560][320] <- Wff1[320][2560]
    int b2 = b - 245; int tn = b2 / 5, tk = b2 - tn*5;
    n0 = tn*64; k0 = tk*64; S = 2560; O = 320; mode = 0; outb = wff1t; src = Wff1; nadj = n0;
  } else if (b < 545) {    // wff2t [320][1280] <- Wff2[1280][320]
    int b2 = b - 445; int tn = b2 / 20, tk = b2 - tn*20;
    n0 = tn*64; k0 = tk*64; S = 320; O = 1280; mode = 0; outb = wff2t; src = Wff2; nadj = n0;
  } else {                 // wq2th/wq2tl dual [320][320] <- Wq2
    int b2 = b - 545; int tn = b2 / 5, tk = b2 - tn*5;
    n0 = tn*64; k0 = tk*64; S = 320; O = 320; mode = 2; src = Wq2; nadj = n0;
  }

  const int r4 = tid >> 6;     // 0..3
  const int c  = tid & 63;
  const float* srcp = src + nadj;
#pragma unroll
  for (int i = 0; i < 16; i++) {
    int r = i*4 + r4;
    T[c][r] = srcp[(size_t)(k0 + r)*S + c] * scale;
  }
  __syncthreads();
#pragma unroll
  for (int i = 0; i < 16; i++) {
    int r = i*4 + r4;
    float v = T[r][c];
    size_t oi = (size_t)(n0 + r)*O + k0 + c;
    if (mode == 0) {
      outb[oi] = f2b(v);
    } else if (mode == 1) {
      outf[oi] = v;
    } else {
      bf16_t h = f2b(v);
      wq2th[oi] = h;
      wq2tl[oi] = f2b(v - b2f(h));
    }
  }
}

// =========================== LayerNorm (ln3) ===========================
template<typename OT>
__global__ __launch_bounds__(256) void ln_kernel(
    const float* __restrict__ x, const float* __restrict__ g, const float* __restrict__ b,
    OT* __restrict__ out)
{
  const int lane = threadIdx.x & 63;
  const int row = blockIdx.x * 4 + (threadIdx.x >> 6);
  const float* xr = x + (size_t)row * 320;
  float v[5], s = 0.f, s2 = 0.f;
#pragma unroll
  for (int i = 0; i < 5; i++) { v[i] = xr[lane + i*64]; s += v[i]; s2 += v[i]*v[i]; }
#pragma unroll
  for (int o = 32; o; o >>= 1) { s += __shfl_xor(s, o); s2 += __shfl_xor(s2, o); }
  float mu = s * (1.f/320.f);
  float rs = rsqrtf(fmaxf(s2*(1.f/320.f) - mu*mu, 0.f) + 1e-5f);
#pragma unroll
  for (int i = 0; i < 5; i++) {
    int c = lane + i*64;
    sto((v[i]-mu)*rs*g[c] + b[c], &out[(size_t)row*320 + c]);
  }
}

// LayerNorm writing hi/lo bf16 split (ln2)
__global__ __launch_bounds__(256) void ln2_split_kernel(
    const float* __restrict__ x, const float* __restrict__ g, const float* __restrict__ b,
    bf16_t* __restrict__ hi, bf16_t* __restrict__ lo)
{
  const int lane = threadIdx.x & 63;
  const int row = blockIdx.x * 4 + (threadIdx.x >> 6);
  const float* xr = x + (size_t)row * 320;
  float v[5], s = 0.f, s2 = 0.f;
#pragma unroll
  for (int i = 0; i < 5; i++) { v[i] = xr[lane + i*64]; s += v[i]; s2 += v[i]*v[i]; }
#pragma unroll
  for (int o = 32; o; o >>= 1) { s += __shfl_xor(s, o); s2 += __shfl_xor(s2, o); }
  float mu = s * (1.f/320.f);
  float rs = rsqrtf(fmaxf(s2*(1.f/320.f) - mu*mu, 0.f) + 1e-5f);
#pragma unroll
  for (int i = 0; i < 5; i++) {
    int c = lane + i*64;
    float y = (v[i]-mu)*rs*g[c] + b[c];
    bf16_t h = f2b(y);
    hi[(size_t)row*320 + c] = h;
    lo[(size_t)row*320 + c] = f2b(y - b2f(h));
  }
}

// =========================== kv2 dot-product GEMM (B-tile in LDS, m-loop in block) ===========================
__global__ __launch_bounds__(256) void kv2_dot_kernel(
    const float* __restrict__ ctx, const float* __restrict__ wkv2t,
    bf16_t* __restrict__ k2h, bf16_t* __restrict__ k2l, bf16_t* __restrict__ v2t)
{
  __shared__ float4 Bs[16][193];
  const int tid = threadIdx.x;
  const int nb = blockIdx.x % 40, ms = blockIdx.x / 40;
  const int n0 = nb*16;
  for (int e = tid; e < 16*192; e += 256) {
    int row = e / 192, c4 = e - row*192;
    Bs[row][c4] = *(const float4*)(wkv2t + (size_t)(n0+row)*768 + c4*4);
  }
  __syncthreads();
  const int g = tid >> 4, q = tid & 15;
  const int mlo = ms*20;
  const int mhi = (mlo + 20 > 77) ? 77 : mlo + 20;
  for (int m = mlo; m < mhi; m++) {
    const float4* a = (const float4*)(ctx + (size_t)m*768);
    float acc = 0.f;
#pragma unroll
    for (int i = 0; i < 12; i++) {
      float4 av = a[i*16+q], bv = Bs[g][i*16+q];
      acc += av.x*bv.x + av.y*bv.y + av.z*bv.z + av.w*bv.w;
    }
#pragma unroll
    for (int o = 8; o; o >>= 1) acc += __shfl_xor(acc, o);
    if (q == 0) {
      int n = n0 + g;
      if (n < 320) {
        int h = n / 40, d = n - h*40;
        int idx = h*6144 + m*64 + d;
        bf16_t hh = f2b(acc);
        k2h[idx] = hh;
        k2l[idx] = f2b(acc - b2f(hh));
      } else {
        int n2 = n - 320; int h = n2 / 40, d = n2 - h*40;
        v2t[h*4608 + d*96 + m] = f2b(acc);
      }
    }
  }
}

// =========================== K/V fragment repack (self-attn) ===========================
__global__ __launch_bounds__(256) void repack_vt_kernel(
    const bf16_t* __restrict__ qkvb, f16_t* __restrict__ vpack, bf16_t* __restrict__ kpack)
{
  __shared__ f16_t T[64*44];
  const int tid = threadIdx.x;
  const int t0 = blockIdx.x * 64, h = blockIdx.y;
  for (int e = tid; e < 320; e += 256) {
    int t = e / 5, c8 = (e - t*5) * 8;
    bf16x8 v = *(const bf16x8*)(qkvb + (size_t)(t0+t)*960 + 640 + h*40 + c8);
    f16_t* dst = &T[t*44 + c8];
#pragma unroll
    for (int j = 0; j < 8; j++) dst[j] = (f16_t)b2f(v[j]);
  }
  __syncthreads();
  // vpack fragments: 3 dt x 2 groups x 512 = 3072 elems
  for (int e = tid; e < 3072; e += 256) {
    int dt = e >> 10;
    int r  = e & 1023;
    int g2 = r >> 9, o = r & 511;
    int lane = o >> 3, j = o & 7;
    int qd = lane >> 4, ln = lane & 15;
    int d = dt*16 + ln;
    int key = g2*32 + ((j & 4) ? 16 : 0) + qd*4 + (j & 3);
    float val;
    if (d < 40)       val = (float)T[key*44 + d];
    else if (d == 40) val = 1.0f;
    else              val = 0.0f;
    vpack[(((size_t)h*3 + dt)*128 + (t0 >> 5) + g2)*512 + o] = (f16_t)val;
  }
  // kpack fragments: 4 groups x 640 elems
  for (int e = tid; e < 2560; e += 256) {
    int g = e / 640, o = e - g*640;
    int key = t0 + g*16;
    bf16_t val;
    if (o < 512) {
      int lane = o >> 3, j = o & 7;
      int qd = lane >> 4, ln = lane & 15;
      val = qkvb[(size_t)(key + ln)*960 + 320 + h*40 + qd*8 + j];
    } else {
      int o2 = o - 512; int ln = o2 >> 3, j = o2 & 7;
      val = qkvb[(size_t)(key + ln)*960 + 320 + h*40 + 32 + j];
    }
    kpack[((size_t)h*256 + (t0 >> 4) + g)*640 + o] = val;
  }
}

// =========================== bf16/f16 MFMA flash self-attention (v10: setprio) ===========================
__global__ __launch_bounds__(512, 4) void flash_self_kernel(
    const bf16_t* __restrict__ qkvb, const bf16_t* __restrict__ kpack,
    const f16_t* __restrict__ vpack,
    bf16_t* __restrict__ o1a)
{
  __shared__ float Red[12288];     // 48 KB: 8 waves x 2 nt x 3 dt x 256 f32
  const int tid = threadIdx.x;
  const int w = tid >> 6, lane = tid & 63;
  const int ln = lane & 15, qd = lane >> 4;
  const int qh = w >> 2, kh = w & 3;
  const int h = blockIdx.x & 7;
  const int q0 = (blockIdx.x >> 3) * 64;

  const int kgbase = h*256 + kh*2;   // kpack group base (16-key groups)
  const int vgbase = h*384 + kh;     // vpack group base (32-key groups, x(dt stride 128))
  const int lko = lane*8;

  bf16x8 zero8 = {};
  bf16x8 bq[2][2];
#pragma unroll
  for (int nt = 0; nt < 2; nt++) {
    const bf16_t* qp = qkvb + (size_t)(q0 + qh*32 + nt*16 + ln)*960 + h*40;
    bq[nt][0] = *(const bf16x8*)(qp + qd*8);
    bq[nt][1] = (qd == 0) ? *(const bf16x8*)(qp + 32) : zero8;
  }

  f32x4 zero4 = {0.f,0.f,0.f,0.f};
  f32x4 oacc[3][2];
#pragma unroll
  for (int a = 0; a < 3; a++)
#pragma unroll
    for (int b = 0; b < 2; b++) oacc[a][b] = zero4;

#define FS_LOADK(DST, K0)                                                       \
  {                                                                             \
    const bf16_t* kp_ = kpack + ((size_t)kgbase + ((K0) >> 4)) * 640;           \
    DST[0][0] = *(const bf16x8*)(kp_ + lko);                                    \
    DST[0][1] = (qd == 0) ? *(const bf16x8*)(kp_ + 512 + ln*8) : zero8;         \
    DST[1][0] = *(const bf16x8*)(kp_ + 640 + lko);                              \
    DST[1][1] = (qd == 0) ? *(const bf16x8*)(kp_ + 1152 + ln*8) : zero8;        \
  }

#define FS_LOADV(DST, K0)                                                       \
  {                                                                             \
    _Pragma("unroll")                                                           \
    for (int dt_ = 0; dt_ < 3; dt_++)                                           \
      DST[dt_] = *(const f16x8*)(vpack + ((size_t)vgbase + dt_*128 + ((K0) >> 5)) * 512 + lko); \
  }

#define FS_COMPUTE(KA, VA)                                                      \
  {                                                                             \
    __builtin_amdgcn_s_setprio(1);                                              \
    _Pragma("unroll")                                                           \
    for (int nt = 0; nt < 2; nt++) {                                            \
      f32x4 s0 = __builtin_amdgcn_mfma_f32_16x16x32_bf16(KA[0][0], bq[nt][0], zero4, 0,0,0); \
      s0 = __builtin_amdgcn_mfma_f32_16x16x32_bf16(KA[0][1], bq[nt][1], s0, 0,0,0); \
      f32x4 s1 = __builtin_amdgcn_mfma_f32_16x16x32_bf16(KA[1][0], bq[nt][0], zero4, 0,0,0); \
      s1 = __builtin_amdgcn_mfma_f32_16x16x32_bf16(KA[1][1], bq[nt][1], s1, 0,0,0); \
      uint4 u_;                                                                 \
      u_.x = pkh2(__builtin_amdgcn_exp2f(s0[0]), __builtin_amdgcn_exp2f(s0[1])); \
      u_.y = pkh2(__builtin_amdgcn_exp2f(s0[2]), __builtin_amdgcn_exp2f(s0[3])); \
      u_.z = pkh2(__builtin_amdgcn_exp2f(s1[0]), __builtin_amdgcn_exp2f(s1[1])); \
      u_.w = pkh2(__builtin_amdgcn_exp2f(s1[2]), __builtin_amdgcn_exp2f(s1[3])); \
      f16x8 pb = *(f16x8*)&u_;                                                  \
      _Pragma("unroll")                                                         \
      for (int dt = 0; dt < 3; dt++)                                            \
        oacc[dt][nt] = __builtin_amdgcn_mfma_f32_16x16x32_f16(VA[dt], pb, oacc[dt][nt], 0,0,0); \
    }                                                                           \
    __builtin_amdgcn_s_setprio(0);                                              \
  }

  bf16x8 ka[2][2], kb[2][2];
  f16x8 va[3], vb[3];
  FS_LOADK(ka, 0);
  FS_LOADV(va, 0);
#pragma unroll 1
  for (int it = 0; it < 32; it += 2) {
    const int k0 = it*128;
    FS_LOADK(kb, k0 + 128);
    FS_LOADV(vb, k0 + 128);
    FS_COMPUTE(ka, va);
    FS_LOADK(ka, (it + 2 < 32) ? (k0 + 256) : 0);  // wrap: harmless garbage prefetch
    FS_LOADV(va, (it + 2 < 32) ? (k0 + 256) : 0);
    FS_COMPUTE(kb, vb);
  }
#undef FS_LOADK
#undef FS_LOADV
#undef FS_COMPUTE

  // ---- epilogue: reduce the 4 kh waves per qh in LDS, normalize, write bf16 o1a ----
#pragma unroll
  for (int nt = 0; nt < 2; nt++)
#pragma unroll
    for (int dt = 0; dt < 3; dt++)
      *(f32x4*)&Red[((w*2 + nt)*3 + dt)*256 + ln*16 + qd*4] = oacc[dt][nt];
  __syncthreads();
  const int dgrp = tid & 7, lq = (tid >> 3) & 15, ntw = (tid >> 7) & 1, qh2 = tid >> 8;
  float l = Red[(((qh2*4 + 0)*2 + ntw)*3 + 2)*256 + lq*16 + 8]
          + Red[(((qh2*4 + 1)*2 + ntw)*3 + 2)*256 + lq*16 + 8]
          + Red[(((qh2*4 + 2)*2 + ntw)*3 + 2)*256 + lq*16 + 8]
          + Red[(((qh2*4 + 3)*2 + ntw)*3 + 2)*256 + lq*16 + 8];
  float inv = 1.f / l;
  bf16_t* obase = o1a + (size_t)(q0 + qh2*32 + ntw*16 + lq)*320 + h*40;
#pragma unroll
  for (int i = 0; i < 5; i++) {
    int d = dgrp + i*8;
    int dt = d >> 4, dr = d & 15;
    float o = Red[(((qh2*4 + 0)*2 + ntw)*3 + dt)*256 + lq*16 + dr]
            + Red[(((qh2*4 + 1)*2 + ntw)*3 + dt)*256 + lq*16 + dr]
            + Red[(((qh2*4 + 2)*2 + ntw)*3 + dt)*256 + lq*16 + dr]
            + Red[(((qh2*4 + 3)*2 + ntw)*3 + dt)*256 + lq*16 + dr];
    obase[d] = f2b(o * inv);
  }
}

// =========================== cross-attention (setprio around MFMA clusters) ===========================
__global__ __launch_bounds__(256) void attn_cross_kernel(
    const float* __restrict__ q2, const bf16_t* __restrict__ k2h, const bf16_t* __restrict__ k2l,
    const bf16_t* __restrict__ famh, const bf16_t* __restrict__ faml,
    const bf16_t* __restrict__ v2t, const int* __restrict__ use_fca,
    bf16_t* __restrict__ o2)
{
  __shared__ bf16_t SMh[4][16*96];
  __shared__ bf16_t SMl[4][16*96];
  __shared__ bf16_t PAs[4][16*96];
  const int tid = threadIdx.x;
  const int w = tid >> 6, lane = tid & 63;
  const int ln = lane & 15, qd = lane >> 4;
  const int h = blockIdx.x & 7;
  const int q0 = (blockIdx.x >> 3)*64 + w*16;
  const int fca = use_fca[0];
  bf16_t* smh = SMh[w];
  bf16_t* sml = SMl[w];
  bf16_t* pa  = PAs[w];

  {
    bf16x4 z = {};
    int q = lane >> 2, c = 80 + (lane & 3)*4;
    *(bf16x4*)&smh[q*96 + c] = z;
    *(bf16x4*)&sml[q*96 + c] = z;
    *(bf16x4*)&pa [q*96 + c] = z;
  }

  bf16x8 zero8 = {};
  bf16x8 aqh0, aql0, aqh1 = zero8, aql1 = zero8;
  {
    const float* qp = q2 + (size_t)(q0 + ln)*320 + h*40;
    float4 v0 = *(const float4*)(qp + qd*8);
    float4 v1 = *(const float4*)(qp + qd*8 + 4);
    float qv[8] = {v0.x,v0.y,v0.z,v0.w,v1.x,v1.y,v1.z,v1.w};
#pragma unroll
    for (int i = 0; i < 8; i++) {
      bf16_t hh = f2b(qv[i]);
      aqh0[i] = hh; aql0[i] = f2b(qv[i] - b2f(hh));
    }
    if (qd == 0) {
      float4 u0 = *(const float4*)(qp + 32);
      float4 u1 = *(const float4*)(qp + 36);
      float uv[8] = {u0.x,u0.y,u0.z,u0.w,u1.x,u1.y,u1.z,u1.w};
#pragma unroll
      for (int i = 0; i < 8; i++) {
        bf16_t hh = f2b(uv[i]);
        aqh1[i] = hh; aql1[i] = f2b(uv[i] - b2f(hh));
      }
    }
  }

  f32x4 zero4 = {0.f,0.f,0.f,0.f};
  float ss[5][4];
  __builtin_amdgcn_s_setprio(1);
#pragma unroll
  for (int nt = 0; nt < 5; nt++) {
    const bf16_t* kb = k2h + ((size_t)h*96 + nt*16 + ln)*64 + qd*8;
    const bf16_t* kl = k2l + ((size_t)h*96 + nt*16 + ln)*64 + qd*8;
    bf16x8 kh0 = *(const bf16x8*)kb;
    bf16x8 kh1 = *(const bf16x8*)(kb + 32);
    bf16x8 kl0 = *(const bf16x8*)kl;
    bf16x8 kl1 = *(const bf16x8*)(kl + 32);
    f32x4 s;
    s = __builtin_amdgcn_mfma_f32_16x16x32_bf16(aqh0, kl0, zero4, 0, 0, 0);
    s = __builtin_amdgcn_mfma_f32_16x16x32_bf16(aql0, kh0, s, 0, 0, 0);
    s = __builtin_amdgcn_mfma_f32_16x16x32_bf16(aqh0, kh0, s, 0, 0, 0);
    s = __builtin_amdgcn_mfma_f32_16x16x32_bf16(aqh1, kl1, s, 0, 0, 0);
    s = __builtin_amdgcn_mfma_f32_16x16x32_bf16(aql1, kh1, s, 0, 0, 0);
    s = __builtin_amdgcn_mfma_f32_16x16x32_bf16(aqh1, kh1, s, 0, 0, 0);
#pragma unroll
    for (int r = 0; r < 4; r++) {
      float sv = s[r] * ATT_SCALE;
      ss[nt][r] = sv;
      bf16_t hh = f2b(sv);
      smh[(qd*4 + r)*96 + nt*16 + ln] = hh;
      sml[(qd*4 + r)*96 + nt*16 + ln] = f2b(sv - b2f(hh));
    }
  }
  __builtin_amdgcn_s_setprio(0);

  f32x4 facc[5];
#pragma unroll
  for (int nt = 0; nt < 5; nt++) facc[nt] = zero4;
  __builtin_amdgcn_s_setprio(1);
#pragma unroll
  for (int c = 0; c < 3; c++) {
    bf16x8 sah = *(const bf16x8*)&smh[ln*96 + c*32 + qd*8];
    bf16x8 sal = *(const bf16x8*)&sml[ln*96 + c*32 + qd*8];
#pragma unroll
    for (int nt = 0; nt < 5; nt++) {
      bf16x8 fh8 = *(const bf16x8*)(famh + ((size_t)(nt*16 + ln))*96 + c*32 + qd*8);
      bf16x8 fl8 = *(const bf16x8*)(faml + ((size_t)(nt*16 + ln))*96 + c*32 + qd*8);
      facc[nt] = __builtin_amdgcn_mfma_f32_16x16x32_bf16(sah, fl8, facc[nt], 0, 0, 0);
      facc[nt] = __builtin_amdgcn_mfma_f32_16x16x32_bf16(sal, fh8, facc[nt], 0, 0, 0);
      facc[nt] = __builtin_amdgcn_mfma_f32_16x16x32_bf16(sah, fh8, facc[nt], 0, 0, 0);
    }
  }
  __builtin_amdgcn_s_setprio(0);

  float pr[5][4];
  if (fca) {
    float fwv[5][4], fm[4];
#pragma unroll
    for (int nt = 0; nt < 5; nt++)
#pragma unroll
      for (int r = 0; r < 4; r++) fwv[nt][r] = fminf(fabsf(facc[nt][r]), 1.f);
#pragma unroll
    for (int r = 0; r < 4; r++) {
      float m = fmaxf(fmaxf(fwv[0][r], fwv[1][r]), fmaxf(fwv[2][r], fmaxf(fwv[3][r], fwv[4][r])));
#pragma unroll
      for (int o = 8; o; o >>= 1) m = fmaxf(m, __shfl_xor(m, o));
      fm[r] = m;
    }
#pragma unroll
    for (int nt = 0; nt < 5; nt++)
#pragma unroll
      for (int r = 0; r < 4; r++) {
        float lg = ss[nt][r] - ((fwv[nt][r] > 0.6f*(fm[r] + 1e-6f)) ? 0.f : 50.f);
        pr[nt][r] = __builtin_amdgcn_exp2f(lg * LOG2E);
      }
  } else {
#pragma unroll
    for (int nt = 0; nt < 5; nt++)
#pragma unroll
      for (int r = 0; r < 4; r++)
        pr[nt][r] = __builtin_amdgcn_exp2f(ss[nt][r] * LOG2E);
  }
  if (ln >= 13) {
#pragma unroll
    for (int r = 0; r < 4; r++) pr[4][r] = 0.f;
  }
  float l_[4] = {0.f,0.f,0.f,0.f};
#pragma unroll
  for (int nt = 0; nt < 5; nt++)
#pragma unroll
    for (int r = 0; r < 4; r++) {
      l_[r] += pr[nt][r];
      pa[(qd*4 + r)*96 + nt*16 + ln] = f2b(pr[nt][r]);
    }
#pragma unroll
  for (int r = 0; r < 4; r++)
#pragma unroll
    for (int o = 8; o; o >>= 1) l_[r] += __shfl_xor(l_[r], o);

  f32x4 oacc[3];
#pragma unroll
  for (int nt = 0; nt < 3; nt++) oacc[nt] = zero4;
  __builtin_amdgcn_s_setprio(1);
#pragma unroll
  for (int c = 0; c < 3; c++) {
    bf16x8 paf = *(const bf16x8*)&pa[ln*96 + c*32 + qd*8];
#pragma unroll
    for (int nt = 0; nt < 3; nt++) {
      bf16x8 vb = *(const bf16x8*)(v2t + ((size_t)h*48 + nt*16 + ln)*96 + c*32 + qd*8);
      oacc[nt] = __builtin_amdgcn_mfma_f32_16x16x32_bf16(paf, vb, oacc[nt], 0, 0, 0);
    }
  }
  __builtin_amdgcn_s_setprio(0);
  float inv[4];
#pragma unroll
  for (int r = 0; r < 4; r++) inv[r] = 1.f / l_[r];
#pragma unroll
  for (int nt = 0; nt < 3; nt++) {
    int d = nt*16 + ln;
    if (d < 40) {
#pragma unroll
      for (int r = 0; r < 4; r++)
        o2[(size_t)(q0 + qd*4 + r)*320 + h*40 + d] = f2b(oacc[nt][r]*inv[r]);
    }
  }
}

// =========================== bf16 MFMA GEMM 128x64 (gl_lds + swizzle + 2-phase dbuf) ===========================
template<int OUT_BF16>
__global__ __launch_bounds__(256) void gemm_bf16_kernel(
    const bf16_t* __restrict__ A, const bf16_t* __restrict__ Bt,
    const float* __restrict__ bias, const float* __restrict__ resid,
    void* __restrict__ Cout, int M, int N, int K)
{
  __shared__ __align__(16) bf16_t As[2][128][64];
  __shared__ __align__(16) bf16_t Bs[2][64][64];
  const int tid = threadIdx.x;
  const int m0 = blockIdx.x * 128, n0 = blockIdx.y * 64;
  const int w = tid >> 6, lane = tid & 63;
  const int wr = w >> 1, wc = w & 1;
  const int ln = lane & 15, qd = lane >> 4;
  const int lr = lane >> 3, lsw = (lane & 7) ^ lr;   // row-in-wave, swizzled source col8
  f32x4 zero = {0.f, 0.f, 0.f, 0.f};
  f32x4 acc[4][2];
#pragma unroll
  for (int a = 0; a < 4; a++)
#pragma unroll
    for (int b = 0; b < 2; b++) acc[a][b] = zero;

#define GB_STAGE(BI, KK)                                                          \
  {                                                                               \
    char* asb_ = (char*)&As[BI][0][0];                                            \
    char* bsb_ = (char*)&Bs[BI][0][0];                                            \
    _Pragma("unroll")                                                             \
    for (int i = 0; i < 4; i++)                                                   \
      gl_lds16(A + (size_t)(m0 + (i*4 + w)*8 + lr)*K + (KK) + lsw*8, asb_ + (i*4 + w)*1024); \
    _Pragma("unroll")                                                             \
    for (int i = 0; i < 2; i++)                                                   \
      gl_lds16(Bt + (size_t)(n0 + (i*4 + w)*8 + lr)*K + (KK) + lsw*8, bsb_ + (i*4 + w)*1024); \
  }

  const int NT = K >> 6;
  GB_STAGE(0, 0)
  __syncthreads();
  for (int t = 0; t < NT; t++) {
    if (t + 1 < NT) GB_STAGE((t + 1) & 1, (t + 1) * 64)
    const int bi = t & 1;
#pragma unroll
    for (int c = 0; c < 2; c++) {
      const int sa = (((c*4 + qd) ^ (ln & 7))) * 8;
      bf16x8 af[4], bfr[2];
#pragma unroll
      for (int mt = 0; mt < 4; mt++)
        af[mt] = *(const bf16x8*)&As[bi][wr*64 + mt*16 + ln][sa];
#pragma unroll
      for (int nt = 0; nt < 2; nt++)
        bfr[nt] = *(const bf16x8*)&Bs[bi][wc*32 + nt*16 + ln][sa];
#pragma unroll
      for (int mt = 0; mt < 4; mt++)
#pragma unroll
        for (int nt = 0; nt < 2; nt++)
          acc[mt][nt] = __builtin_amdgcn_mfma_f32_16x16x32_bf16(af[mt], bfr[nt], acc[mt][nt], 0, 0, 0);
    }
    __syncthreads();
  }
#undef GB_STAGE
#pragma unroll
  for (int mt = 0; mt < 4; mt++)
#pragma unroll
    for (int nt = 0; nt < 2; nt++)
#pragma unroll
      for (int r = 0; r < 4; r++) {
        int gm = m0 + wr*64 + mt*16 + qd*4 + r;
        int gn = n0 + wc*32 + nt*16 + ln;
        float v = acc[mt][nt][r];
        if (bias)  v += bias[gn];
        if (resid) v += resid[(size_t)gm*N + gn];
        if (OUT_BF16) sto(v, &((bf16_t*)Cout)[(size_t)gm*N + gn]);
        else          sto(v, &((float*)Cout)[(size_t)gm*N + gn]);
      }
}

// =========================== bf16 MFMA GEMM 32x64 (gl_lds + swizzle + 2-phase dbuf) ===========================
template<int OUT_BF16>
__global__ __launch_bounds__(256) void gemm_bf16_32_kernel(
    const bf16_t* __restrict__ A, const bf16_t* __restrict__ Bt,
    const float* __restrict__ bias, const float* __restrict__ resid,
    void* __restrict__ Cout, int M, int N, int K)
{
  __shared__ __align__(16) bf16_t As[2][32][64];
  __shared__ __align__(16) bf16_t Bs[2][64][64];
  const int tid = threadIdx.x;
  const int m0 = blockIdx.x * 32, n0 = blockIdx.y * 64;
  const int w = tid >> 6, lane = tid & 63;
  const int wr = w >> 1, wc = w & 1;
  const int ln = lane & 15, qd = lane >> 4;
  const int lr = lane >> 3, lsw = (lane & 7) ^ lr;
  f32x4 zero = {0.f, 0.f, 0.f, 0.f};
  f32x4 acc[2];
  acc[0] = zero; acc[1] = zero;

#define GB32_STAGE(BI, KK)                                                        \
  {                                                                               \
    char* asb_ = (char*)&As[BI][0][0];                                            \
    char* bsb_ = (char*)&Bs[BI][0][0];                                            \
    gl_lds16(A + (size_t)(m0 + w*8 + lr)*K + (KK) + lsw*8, asb_ + w*1024);        \
    _Pragma("unroll")                                                             \
    for (int i = 0; i < 2; i++)                                                   \
      gl_lds16(Bt + (size_t)(n0 + (i*4 + w)*8 + lr)*K + (KK) + lsw*8, bsb_ + (i*4 + w)*1024); \
  }

  const int NT = K >> 6;
  GB32_STAGE(0, 0)
  __syncthreads();
  for (int t = 0; t < NT; t++) {
    if (t + 1 < NT) GB32_STAGE((t + 1) & 1, (t + 1) * 64)
    const int bi = t & 1;
#pragma unroll
    for (int c = 0; c < 2; c++) {
      const int sa = (((c*4 + qd) ^ (ln & 7))) * 8;
      bf16x8 af = *(const bf16x8*)&As[bi][wr*16 + ln][sa];
#pragma unroll
      for (int nt = 0; nt < 2; nt++) {
        bf16x8 bfr = *(const bf16x8*)&Bs[bi][wc*32 + nt*16 + ln][sa];
        acc[nt] = __builtin_amdgcn_mfma_f32_16x16x32_bf16(af, bfr, acc[nt], 0, 0, 0);
      }
    }
    __syncthreads();
  }
#undef GB32_STAGE
#pragma unroll
  for (int nt = 0; nt < 2; nt++)
#pragma unroll
    for (int r = 0; r < 4; r++) {
      int gm = m0 + wr*16 + qd*4 + r;
      int gn = n0 + wc*32 + nt*16 + ln;
      float v = acc[nt][r];
      if (bias)  v += bias[gn];
      if (resid) v += resid[(size_t)gm*N + gn];
      if (OUT_BF16) sto(v, &((bf16_t*)Cout)[(size_t)gm*N + gn]);
      else          sto(v, &((float*)Cout)[(size_t)gm*N + gn]);
    }
}

// =========================== 3-term bf16 MFMA GEMM (v2: gl_lds + swizzle + 2-phase dbuf) ===========================
// Same proven combo as the other GEMMs, applied to the 4-panel fp32-emulation GEMM.
// LDS 48 KB (2 x 24 KB), ~3 blocks/CU; 24 MFMA per k-iter amortizes the barrier.
__global__ __launch_bounds__(256) void gemm3_32_kernel(
    const bf16_t* __restrict__ Ah, const bf16_t* __restrict__ Al,
    const bf16_t* __restrict__ Bth, const bf16_t* __restrict__ Btl,
    float* __restrict__ C, int M, int N, int K)
{
  __shared__ __align__(16) bf16_t Ash[2][32][64];
  __shared__ __align__(16) bf16_t Asl[2][32][64];
  __shared__ __align__(16) bf16_t Bsh[2][64][64];
  __shared__ __align__(16) bf16_t Bsl[2][64][64];
  const int tid = threadIdx.x;
  const int m0 = blockIdx.x * 32, n0 = blockIdx.y * 64;
  const int w = tid >> 6, lane = tid & 63;
  const int wr = w >> 1, wc = w & 1;
  const int ln = lane & 15, qd = lane >> 4;
  const int lr = lane >> 3, lsw = (lane & 7) ^ lr;
  f32x4 zero = {0.f, 0.f, 0.f, 0.f};
  f32x4 acc[2];
  acc[0] = zero; acc[1] = zero;

#define G3_STAGE(BI, KK)                                                          \
  {                                                                               \
    char* ash_ = (char*)&Ash[BI][0][0];                                           \
    char* asl_ = (char*)&Asl[BI][0][0];                                           \
    char* bsh_ = (char*)&Bsh[BI][0][0];                                           \
    char* bsl_ = (char*)&Bsl[BI][0][0];                                           \
    gl_lds16(Ah + (size_t)(m0 + w*8 + lr)*K + (KK) + lsw*8, ash_ + w*1024);       \
    gl_lds16(Al + (size_t)(m0 + w*8 + lr)*K + (KK) + lsw*8, asl_ + w*1024);       \
    _Pragma("unroll")                                                             \
    for (int i = 0; i < 2; i++) {                                                 \
      gl_lds16(Bth + (size_t)(n0 + (i*4 + w)*8 + lr)*K + (KK) + lsw*8, bsh_ + (i*4 + w)*1024); \
      gl_lds16(Btl + (size_t)(n0 + (i*4 + w)*8 + lr)*K + (KK) + lsw*8, bsl_ + (i*4 + w)*1024); \
    }                                                                             \
  }

  const int NT = K >> 6;
  G3_STAGE(0, 0)
  __syncthreads();
  for (int t = 0; t < NT; t++) {
    if (t + 1 < NT) G3_STAGE((t + 1) & 1, (t + 1) * 64)
    const int bi = t & 1;
#pragma unroll
    for (int c = 0; c < 2; c++) {
      const int sa = (((c*4 + qd) ^ (ln & 7))) * 8;
      bf16x8 afh = *(const bf16x8*)&Ash[bi][wr*16 + ln][sa];
      bf16x8 afl = *(const bf16x8*)&Asl[bi][wr*16 + ln][sa];
#pragma unroll
      for (int nt = 0; nt < 2; nt++) {
        bf16x8 bfh = *(const bf16x8*)&Bsh[bi][wc*32 + nt*16 + ln][sa];
        bf16x8 bfl = *(const bf16x8*)&Bsl[bi][wc*32 + nt*16 + ln][sa];
        acc[nt] = __builtin_amdgcn_mfma_f32_16x16x32_bf16(afh, bfl, acc[nt], 0, 0, 0);
        acc[nt] = __builtin_amdgcn_mfma_f32_16x16x32_bf16(afl, bfh, acc[nt], 0, 0, 0);
        acc[nt] = __builtin_amdgcn_mfma_f32_16x16x32_bf16(afh, bfh, acc[nt], 0, 0, 0);
      }
    }
    __syncthreads();
  }
#undef G3_STAGE
#pragma unroll
  for (int nt = 0; nt < 2; nt++)
#pragma unroll
    for (int r = 0; r < 4; r++) {
      int gm = m0 + wr*16 + qd*4 + r;
      int gn = n0 + wc*32 + nt*16 + ln;
      C[(size_t)gm*N + gn] = acc[nt][r];
    }
}

// =========================== fused FF1 GEMM + GEGLU (gl_lds + swizzle, single-buffered) ===========================
__global__ __launch_bounds__(256) void gemm_geglu_kernel(
    const bf16_t* __restrict__ A, const bf16_t* __restrict__ Bt,
    const float* __restrict__ bias, bf16_t* __restrict__ gg, int K)
{
  __shared__ __align__(16) bf16_t As[128][64];
  __shared__ __align__(16) bf16_t Ba[64][64];
  __shared__ __align__(16) bf16_t Bg[64][64];
  const int tid = threadIdx.x;
  const int m0 = blockIdx.x * 128, n0 = blockIdx.y * 64;
  const int w = tid >> 6, lane = tid & 63;
  const int wr = w >> 1, wc = w & 1;
  const int ln = lane & 15, qd = lane >> 4;
  const int lr = lane >> 3, lsw = (lane & 7) ^ lr;
  char* asb = (char*)&As[0][0];
  char* bab = (char*)&Ba[0][0];
  char* bgb = (char*)&Bg[0][0];
  f32x4 zero = {0.f, 0.f, 0.f, 0.f};
  f32x4 acca[4][2], accg[4][2];
#pragma unroll
  for (int a = 0; a < 4; a++)
#pragma unroll
    for (int b = 0; b < 2; b++) { acca[a][b] = zero; accg[a][b] = zero; }

  for (int k0 = 0; k0 < K; k0 += 64) {
    __syncthreads();
#pragma unroll
    for (int i = 0; i < 4; i++)
      gl_lds16(A + (size_t)(m0 + (i*4 + w)*8 + lr)*K + k0 + lsw*8, asb + (i*4 + w)*1024);
#pragma unroll
    for (int i = 0; i < 2; i++) {
      gl_lds16(Bt + (size_t)(n0 + (i*4 + w)*8 + lr)*K + k0 + lsw*8, bab + (i*4 + w)*1024);
      gl_lds16(Bt + (size_t)(n0 + 1280 + (i*4 + w)*8 + lr)*K + k0 + lsw*8, bgb + (i*4 + w)*1024);
    }
    __syncthreads();
#pragma unroll
    for (int c = 0; c < 2; c++) {
      const int sa = (((c*4 + qd) ^ (ln & 7))) * 8;
      bf16x8 af[4], ba[2], bg[2];
#pragma unroll
      for (int mt = 0; mt < 4; mt++)
        af[mt] = *(const bf16x8*)&As[wr*64 + mt*16 + ln][sa];
#pragma unroll
      for (int nt = 0; nt < 2; nt++) {
        ba[nt] = *(const bf16x8*)&Ba[wc*32 + nt*16 + ln][sa];
        bg[nt] = *(const bf16x8*)&Bg[wc*32 + nt*16 + ln][sa];
      }
#pragma unroll
      for (int mt = 0; mt < 4; mt++)
#pragma unroll
        for (int nt = 0; nt < 2; nt++) {
          acca[mt][nt] = __builtin_amdgcn_mfma_f32_16x16x32_bf16(af[mt], ba[nt], acca[mt][nt], 0, 0, 0);
          accg[mt][nt] = __builtin_amdgcn_mfma_f32_16x16x32_bf16(af[mt], bg[nt], accg[mt][nt], 0, 0, 0);
        }
    }
  }
#pragma unroll
  for (int mt = 0; mt < 4; mt++)
#pragma unroll
    for (int nt = 0; nt < 2; nt++)
#pragma unroll
      for (int r = 0; r < 4; r++) {
        int gm = m0 + wr*64 + mt*16 + qd*4 + r;
        int gn = n0 + wc*32 + nt*16 + ln;
        float va = acca[mt][nt][r] + bias[gn];
        float vg = accg[mt][nt][r] + bias[1280 + gn];
        float ge = 0.5f * vg * (1.f + erff(vg * 0.70710678118654752f));
        gg[(size_t)gm*1280 + gn] = f2b(va * ge);
      }
}

// =========================== launch ===========================
extern "C" void kernel_launch(void* const* d_in, const int* in_sizes, int n_in,
                              void* d_out, int out_size, void* d_ws, size_t ws_size,
                              hipStream_t stream)
{
  const float* x    = (const float*)d_in[0];
  const float* ctx  = (const float*)d_in[1];
  const float* fam  = (const float*)d_in[2];
  const float* g1   = (const float*)d_in[3];
  const float* b1   = (const float*)d_in[4];
  const float* g2   = (const float*)d_in[5];
  const float* b2   = (const float*)d_in[6];
  const float* g3   = (const float*)d_in[7];
  const float* b3   = (const float*)d_in[8];
  const float* Wq1  = (const float*)d_in[9];
  const float* Wk1  = (const float*)d_in[10];
  const float* Wv1  = (const float*)d_in[11];
  const float* Wo1  = (const float*)d_in[12];
  const float* bo1  = (const float*)d_in[13];
  const float* Wq2  = (const float*)d_in[14];
  const float* Wk2  = (const float*)d_in[15];
  const float* Wv2  = (const float*)d_in[16];
  const float* Wo2  = (const float*)d_in[17];
  const float* bo2  = (const float*)d_in[18];
  const float* Wff1 = (const float*)d_in[19];
  const float* bff1 = (const float*)d_in[20];
  const float* Wff2 = (const float*)d_in[21];
  const float* bff2 = (const float*)d_in[22];
  const int*   ufca = (const int*)d_in[23];

  char* ws = (char*)d_ws;
  bf16_t* qkvb = (bf16_t*)(ws + 0);          //  7,864,320  bf16 [4096][960] (Q pre-scaled)
  f16_t*  vpack = (f16_t*)(ws + 7864320);    //  3,145,728  f16 [8][3][128][512] fragment-packed V
  bf16_t* kpack = (bf16_t*)(ws + 11010048);  //  2,621,440  bf16 [8][256][640]
  bf16_t* h1b  = (bf16_t*)(ws + 13631488);   //  2,621,440
  bf16_t* h2hi = (bf16_t*)(ws + 16252928);   //  2,621,440
  bf16_t* h2lo = (bf16_t*)(ws + 18874368);   //  2,621,440
  float*  x2   = (float*)(ws + 21495808);    //  5,242,880
  float*  q2   = (float*)(ws + 26738688);    //  5,242,880
  bf16_t* o1a  = (bf16_t*)(ws + 26738688);   //  2,621,440  bf16 [4096][320] (overlays q2: o1a dead
                                             //             before gemm3 writes q2; flash->wo1 only)
  bf16_t* o2   = (bf16_t*)(ws + 32178688);   //  2,621,440
  float*  x3   = (float*)(ws + 34800128);    //  5,242,880
  bf16_t* h3b  = (bf16_t*)(ws + 40043008);   //  2,621,440
  bf16_t* wqkvt = (bf16_t*)(ws + 42664448);  //    614,400
  bf16_t* wo1t  = (bf16_t*)(ws + 43278848);  //    204,800
  float*  wkv2t = (float*)(ws + 43483648);   //  1,966,080
  bf16_t* wo2t  = (bf16_t*)(ws + 45449728);  //    204,800
  bf16_t* wff1t = (bf16_t*)(ws + 45654528);  //  1,638,400
  bf16_t* wff2t = (bf16_t*)(ws + 47292928);  //    819,200
  bf16_t* wq2th = (bf16_t*)(ws + 48374272);  //    204,800
  bf16_t* wq2tl = (bf16_t*)(ws + 48579072);  //    204,800
  bf16_t* famh  = (bf16_t*)(ws + 48783872);  //     18,432
  bf16_t* faml  = (bf16_t*)(ws + 48802304);  //     18,432
  bf16_t* k2h   = (bf16_t*)(ws + 48820736);  //     98,304
  bf16_t* k2l   = (bf16_t*)(ws + 48919040);  //     98,304
  bf16_t* v2t   = (bf16_t*)(ws + 49017344);  //     73,728  -> end 49,091,072 (k2h..v2t contiguous = zpad)
  bf16_t* gg   = (bf16_t*)(ws + 21495808);   // bf16 [4096][1280] (FF phase; overlays x2,q2)

  float* xout = (float*)d_out;

  // 1: prep + LN1 (merged, independent block ranges)
  prep_ln_kernel<<<1658, 256, 0, stream>>>(Wq1, Wk1, Wv1, Wo1, Wq2, Wk2, Wv2, Wo2, Wff1, Wff2, fam,
                                           wqkvt, wo1t, wkv2t, wo2t, wff1t, wff2t, wq2th, wq2tl,
                                           famh, faml, k2h, x, g1, b1, h1b);
  // --- attn1 (bf16/f16 MFMA flash) ---
  gemm_bf16_kernel<1><<<dim3(32,15), 256, 0, stream>>>(h1b, wqkvt, nullptr, nullptr, qkvb, 4096, 960, 320);
  repack_vt_kernel<<<dim3(64,8), 256, 0, stream>>>(qkvb, vpack, kpack);
  flash_self_kernel<<<512, 512, 0, stream>>>(qkvb, kpack, vpack, o1a);
  gemm_bf16_32_kernel<0><<<dim3(128,5), 256, 0, stream>>>(o1a, wo1t, bo1, x, x2, 4096, 320, 320);
  // --- attn2 (ln2_split + gemm3_32) ---
  ln2_split_kernel<<<1024, 256, 0, stream>>>(x2, g2, b2, h2hi, h2lo);
  gemm3_32_kernel<<<dim3(128,5), 256, 0, stream>>>(h2hi, h2lo, wq2th, wq2tl, q2, 4096, 320, 320);
  kv2_dot_kernel<<<160, 256, 0, stream>>>(ctx, wkv2t, k2h, k2l, v2t);
  attn_cross_kernel<<<512, 256, 0, stream>>>(q2, k2h, k2l, famh, faml, v2t, ufca, o2);
  gemm_bf16_32_kernel<0><<<dim3(128,5), 256, 0, stream>>>(o2, wo2t, bo2, x2, x3, 4096, 320, 320);
  // --- GEGLU FF (fused FF1+GEGLU) ---
  ln_kernel<bf16_t><<<1024, 256, 0, stream>>>(x3, g3, b3, h3b);
  gemm_geglu_kernel<<<dim3(32,20), 256, 0, stream>>>(h3b, wff1t, bff1, gg, 320);
  gemm_bf16_32_kernel<0><<<dim3(128,5), 256, 0, stream>>>(gg, wff2t, bff2, x3, xout, 4096, 320, 1280);
}

// Round 13
// 248.510 us; speedup vs baseline: 1.0069x; 1.0069x over previous
//
#include <hip/hip_runtime.h>
#include <math.h>

typedef __bf16 bf16_t;
typedef __bf16 bf16x8 __attribute__((ext_vector_type(8)));
typedef __bf16 bf16x4 __attribute__((ext_vector_type(4)));
typedef float  f32x4  __attribute__((ext_vector_type(4)));
typedef _Float16 f16_t;
typedef _Float16 f16x4 __attribute__((ext_vector_type(4)));
typedef _Float16 f16x8 __attribute__((ext_vector_type(8)));
typedef __fp16 hf16x2 __attribute__((ext_vector_type(2)));

static constexpr float ATT_SCALE = 0.15811388300841897f; // 40^-0.5
static constexpr float SC2 = 0.22811031f;                // ATT_SCALE * log2(e)
static constexpr float LOG2E = 1.4426950408889634f;

__device__ __forceinline__ bf16_t f2b(float f) {
  unsigned u = __float_as_uint(f);
  u = (u + 0x7fffu + ((u >> 16) & 1u)) >> 16;   // RNE
  unsigned short s = (unsigned short)u;
  bf16_t r;
  *(unsigned short*)&r = s;
  return r;
}
__device__ __forceinline__ float b2f(bf16_t b) {
  unsigned short s = *(const unsigned short*)&b;
  return __uint_as_float(((unsigned)s) << 16);
}
__device__ __forceinline__ void sto(float v, float* p)  { *p = v; }
__device__ __forceinline__ void sto(float v, bf16_t* p) { *p = f2b(v); }
__device__ __forceinline__ unsigned pkh2(float a, float b) {
  hf16x2 h = __builtin_amdgcn_cvt_pkrtz(a, b);
  return *(unsigned*)&h;
}
// Direct global->LDS DMA, 16B per lane. lptr must be WAVE-UNIFORM; HW scatters lane i
// to lptr + i*16. Global address is per-lane (enables source-side swizzle, guide rule #21).
__device__ __forceinline__ void gl_lds16(const void* g, void* l) {
  __builtin_amdgcn_global_load_lds((const __attribute__((address_space(1))) unsigned*)g,
                                   (__attribute__((address_space(3))) unsigned*)l, 16, 0, 0);
}

// =========================== fused weight repack + LN1 (launch-merge) ===========================
__global__ __launch_bounds__(256) void prep_ln_kernel(
    const float* __restrict__ Wq1, const float* __restrict__ Wk1, const float* __restrict__ Wv1,
    const float* __restrict__ Wo1, const float* __restrict__ Wq2,
    const float* __restrict__ Wk2, const float* __restrict__ Wv2, const float* __restrict__ Wo2,
    const float* __restrict__ Wff1, const float* __restrict__ Wff2,
    const float* __restrict__ fam,
    bf16_t* __restrict__ wqkvt, bf16_t* __restrict__ wo1t, float* __restrict__ wkv2t,
    bf16_t* __restrict__ wo2t, bf16_t* __restrict__ wff1t, bf16_t* __restrict__ wff2t,
    bf16_t* __restrict__ wq2th, bf16_t* __restrict__ wq2tl,
    bf16_t* __restrict__ famh, bf16_t* __restrict__ faml,
    bf16_t* __restrict__ zpad,
    const float* __restrict__ x, const float* __restrict__ g1, const float* __restrict__ b1,
    bf16_t* __restrict__ h1b)
{
  const int b = blockIdx.x;
  const int tid = threadIdx.x;

  if (b >= 634) {   // ---- LN1 path ----
    const int bb = b - 634;
    const int lane = tid & 63;
    const int row = bb * 4 + (tid >> 6);
    const float* xr = x + (size_t)row * 320;
    float v[5], s = 0.f, s2 = 0.f;
#pragma unroll
    for (int i = 0; i < 5; i++) { v[i] = xr[lane + i*64]; s += v[i]; s2 += v[i]*v[i]; }
#pragma unroll
    for (int o = 32; o; o >>= 1) { s += __shfl_xor(s, o); s2 += __shfl_xor(s2, o); }
    float mu = s * (1.f/320.f);
    float rs = rsqrtf(fmaxf(s2*(1.f/320.f) - mu*mu, 0.f) + 1e-5f);
#pragma unroll
    for (int i = 0; i < 5; i++) {
      int c = lane + i*64;
      h1b[(size_t)row*320 + c] = f2b((v[i]-mu)*rs*g1[c] + b1[c]);
    }
    return;
  }

  if (b >= 570) {   // ---- elementwise tail: fam (9216) + zpad (135168) ----
    for (int idx = (b - 570)*256 + tid; idx < 9216 + 135168; idx += 64*256) {
      if (idx < 9216) {
        int d = idx / 96, k = idx - d*96;
        float v = (d < 77 && k < 77) ? fam[d*77 + k] : 0.f;
        bf16_t h = f2b(v);
        famh[idx] = h;
        faml[idx] = f2b(v - b2f(h));
      } else {
        zpad[idx - 9216] = f2b(0.f);
      }
    }
    return;
  }

  // ---- tile transpose path ----
  __shared__ float T[64][65];
  const float* src; int S, O, n0, k0, mode;   // mode: 0=bf16, 1=f32, 2=dual hi/lo
  float scale = 1.f;
  bf16_t* outb = nullptr; float* outf = nullptr;
  int nadj;

  if (b < 75) {            // wqkvt [960][320] <- {Wq1*SC2, Wk1, Wv1}[320][320]
    int tn = b / 5, tk = b - tn*5;
    n0 = tn*64; k0 = tk*64; S = 320; O = 320; mode = 0; outb = wqkvt;
    if (n0 < 320)      { src = Wq1; nadj = n0;       scale = SC2; }
    else if (n0 < 640) { src = Wk1; nadj = n0 - 320; }
    else               { src = Wv1; nadj = n0 - 640; }
  } else if (b < 100) {    // wo1t [320][320] <- Wo1
    int b2 = b - 75; int tn = b2 / 5, tk = b2 - tn*5;
    n0 = tn*64; k0 = tk*64; S = 320; O = 320; mode = 0; outb = wo1t; src = Wo1; nadj = n0;
  } else if (b < 220) {    // wkv2t f32 [640][768] <- {Wk2, Wv2}[768][320]
    int b2 = b - 100; int tn = b2 / 12, tk = b2 - tn*12;
    n0 = tn*64; k0 = tk*64; S = 320; O = 768; mode = 1; outf = wkv2t;
    if (n0 < 320) { src = Wk2; nadj = n0; } else { src = Wv2; nadj = n0 - 320; }
  } else if (b < 245) {    // wo2t [320][320] <- Wo2
    int b2 = b - 220; int tn = b2 / 5, tk = b2 - tn*5;
    n0 = tn*64; k0 = tk*64; S = 320; O = 320; mode = 0; outb = wo2t; src = Wo2; nadj = n0;
  } else if (b < 445) {    // wff1t [2560][320] <- Wff1[320][2560]
    int b2 = b - 245; int tn = b2 / 5, tk = b2 - tn*5;
    n0 = tn*64; k0 = tk*64; S = 2560; O = 320; mode = 0; outb = wff1t; src = Wff1; nadj = n0;
  } else if (b < 545) {    // wff2t [320][1280] <- Wff2[1280][320]
    int b2 = b - 445; int tn = b2 / 20, tk = b2 - tn*20;
    n0 = tn*64; k0 = tk*64; S = 320; O = 1280; mode = 0; outb = wff2t; src = Wff2; nadj = n0;
  } else {                 // wq2th/wq2tl dual [320][320] <- Wq2
    int b2 = b - 545; int tn = b2 / 5, tk = b2 - tn*5;
    n0 = tn*64; k0 = tk*64; S = 320; O = 320; mode = 2; src = Wq2; nadj = n0;
  }

  const int r4 = tid >> 6;     // 0..3
  const int c  = tid & 63;
  const float* srcp = src + nadj;
#pragma unroll
  for (int i = 0; i < 16; i++) {
    int r = i*4 + r4;
    T[c][r] = srcp[(size_t)(k0 + r)*S + c] * scale;
  }
  __syncthreads();
#pragma unroll
  for (int i = 0; i < 16; i++) {
    int r = i*4 + r4;
    float v = T[r][c];
    size_t oi = (size_t)(n0 + r)*O + k0 + c;
    if (mode == 0) {
      outb[oi] = f2b(v);
    } else if (mode == 1) {
      outf[oi] = v;
    } else {
      bf16_t h = f2b(v);
      wq2th[oi] = h;
      wq2tl[oi] = f2b(v - b2f(h));
    }
  }
}

// =========================== LayerNorm (ln3) ===========================
template<typename OT>
__global__ __launch_bounds__(256) void ln_kernel(
    const float* __restrict__ x, const float* __restrict__ g, const float* __restrict__ b,
    OT* __restrict__ out)
{
  const int lane = threadIdx.x & 63;
  const int row = blockIdx.x * 4 + (threadIdx.x >> 6);
  const float* xr = x + (size_t)row * 320;
  float v[5], s = 0.f, s2 = 0.f;
#pragma unroll
  for (int i = 0; i < 5; i++) { v[i] = xr[lane + i*64]; s += v[i]; s2 += v[i]*v[i]; }
#pragma unroll
  for (int o = 32; o; o >>= 1) { s += __shfl_xor(s, o); s2 += __shfl_xor(s2, o); }
  float mu = s * (1.f/320.f);
  float rs = rsqrtf(fmaxf(s2*(1.f/320.f) - mu*mu, 0.f) + 1e-5f);
#pragma unroll
  for (int i = 0; i < 5; i++) {
    int c = lane + i*64;
    sto((v[i]-mu)*rs*g[c] + b[c], &out[(size_t)row*320 + c]);
  }
}

// LayerNorm writing hi/lo bf16 split (ln2)
__global__ __launch_bounds__(256) void ln2_split_kernel(
    const float* __restrict__ x, const float* __restrict__ g, const float* __restrict__ b,
    bf16_t* __restrict__ hi, bf16_t* __restrict__ lo)
{
  const int lane = threadIdx.x & 63;
  const int row = blockIdx.x * 4 + (threadIdx.x >> 6);
  const float* xr = x + (size_t)row * 320;
  float v[5], s = 0.f, s2 = 0.f;
#pragma unroll
  for (int i = 0; i < 5; i++) { v[i] = xr[lane + i*64]; s += v[i]; s2 += v[i]*v[i]; }
#pragma unroll
  for (int o = 32; o; o >>= 1) { s += __shfl_xor(s, o); s2 += __shfl_xor(s2, o); }
  float mu = s * (1.f/320.f);
  float rs = rsqrtf(fmaxf(s2*(1.f/320.f) - mu*mu, 0.f) + 1e-5f);
#pragma unroll
  for (int i = 0; i < 5; i++) {
    int c = lane + i*64;
    float y = (v[i]-mu)*rs*g[c] + b[c];
    bf16_t h = f2b(y);
    hi[(size_t)row*320 + c] = h;
    lo[(size_t)row*320 + c] = f2b(y - b2f(h));
  }
}

// =========================== kv2 dot-product GEMM (B-tile in LDS, m-loop in block) ===========================
__global__ __launch_bounds__(256) void kv2_dot_kernel(
    const float* __restrict__ ctx, const float* __restrict__ wkv2t,
    bf16_t* __restrict__ k2h, bf16_t* __restrict__ k2l, bf16_t* __restrict__ v2t)
{
  __shared__ float4 Bs[16][193];
  const int tid = threadIdx.x;
  const int nb = blockIdx.x % 40, ms = blockIdx.x / 40;
  const int n0 = nb*16;
  for (int e = tid; e < 16*192; e += 256) {
    int row = e / 192, c4 = e - row*192;
    Bs[row][c4] = *(const float4*)(wkv2t + (size_t)(n0+row)*768 + c4*4);
  }
  __syncthreads();
  const int g = tid >> 4, q = tid & 15;
  const int mlo = ms*20;
  const int mhi = (mlo + 20 > 77) ? 77 : mlo + 20;
  for (int m = mlo; m < mhi; m++) {
    const float4* a = (const float4*)(ctx + (size_t)m*768);
    float acc = 0.f;
#pragma unroll
    for (int i = 0; i < 12; i++) {
      float4 av = a[i*16+q], bv = Bs[g][i*16+q];
      acc += av.x*bv.x + av.y*bv.y + av.z*bv.z + av.w*bv.w;
    }
#pragma unroll
    for (int o = 8; o; o >>= 1) acc += __shfl_xor(acc, o);
    if (q == 0) {
      int n = n0 + g;
      if (n < 320) {
        int h = n / 40, d = n - h*40;
        int idx = h*6144 + m*64 + d;
        bf16_t hh = f2b(acc);
        k2h[idx] = hh;
        k2l[idx] = f2b(acc - b2f(hh));
      } else {
        int n2 = n - 320; int h = n2 / 40, d = n2 - h*40;
        v2t[h*4608 + d*96 + m] = f2b(acc);
      }
    }
  }
}

// =========================== K/V fragment repack (self-attn) ===========================
__global__ __launch_bounds__(256) void repack_vt_kernel(
    const bf16_t* __restrict__ qkvb, f16_t* __restrict__ vpack, bf16_t* __restrict__ kpack)
{
  __shared__ f16_t T[64*44];
  const int tid = threadIdx.x;
  const int t0 = blockIdx.x * 64, h = blockIdx.y;
  for (int e = tid; e < 320; e += 256) {
    int t = e / 5, c8 = (e - t*5) * 8;
    bf16x8 v = *(const bf16x8*)(qkvb + (size_t)(t0+t)*960 + 640 + h*40 + c8);
    f16_t* dst = &T[t*44 + c8];
#pragma unroll
    for (int j = 0; j < 8; j++) dst[j] = (f16_t)b2f(v[j]);
  }
  __syncthreads();
  // vpack fragments: 3 dt x 2 groups x 512 = 3072 elems
  for (int e = tid; e < 3072; e += 256) {
    int dt = e >> 10;
    int r  = e & 1023;
    int g2 = r >> 9, o = r & 511;
    int lane = o >> 3, j = o & 7;
    int qd = lane >> 4, ln = lane & 15;
    int d = dt*16 + ln;
    int key = g2*32 + ((j & 4) ? 16 : 0) + qd*4 + (j & 3);
    float val;
    if (d < 40)       val = (float)T[key*44 + d];
    else if (d == 40) val = 1.0f;
    else              val = 0.0f;
    vpack[(((size_t)h*3 + dt)*128 + (t0 >> 5) + g2)*512 + o] = (f16_t)val;
  }
  // kpack fragments: 4 groups x 640 elems
  for (int e = tid; e < 2560; e += 256) {
    int g = e / 640, o = e - g*640;
    int key = t0 + g*16;
    bf16_t val;
    if (o < 512) {
      int lane = o >> 3, j = o & 7;
      int qd = lane >> 4, ln = lane & 15;
      val = qkvb[(size_t)(key + ln)*960 + 320 + h*40 + qd*8 + j];
    } else {
      int o2 = o - 512; int ln = o2 >> 3, j = o2 & 7;
      val = qkvb[(size_t)(key + ln)*960 + 320 + h*40 + 32 + j];
    }
    kpack[((size_t)h*256 + (t0 >> 4) + g)*640 + o] = val;
  }
}

// =========================== bf16/f16 MFMA flash self-attention (v11: 4-wave / q-tile 32, 6 blocks/CU) ===========================
// v10 ran grid 512 x 8 waves = 2 blocks/CU = 16 waves/CU (50%). v11: 256-thread blocks,
// q-tile 32 (grid 1024 = qb128 x h8), waves = 4 kh slices; per-wave inner loop is byte-identical
// to v10 (2 nt x 32-key slice x 32 iters, distance-1 K/V prefetch, setprio). Red LDS halves to
// 24KB -> 6 blocks/CU = 24 waves/CU (75%): more TLP to hide the same per-wave latency.
__global__ __launch_bounds__(256, 4) void flash_self_kernel(
    const bf16_t* __restrict__ qkvb, const bf16_t* __restrict__ kpack,
    const f16_t* __restrict__ vpack,
    bf16_t* __restrict__ o1a)
{
  __shared__ float Red[6144];      // 24 KB: 4 waves x 2 nt x 3 dt x 256 f32
  const int tid = threadIdx.x;
  const int w = tid >> 6, lane = tid & 63;    // w = kh (0..3)
  const int ln = lane & 15, qd = lane >> 4;
  const int h = blockIdx.x & 7;
  const int q0 = (blockIdx.x >> 3) * 32;

  const int kgbase = h*256 + w*2;    // kpack group base (16-key groups)
  const int vgbase = h*384 + w;      // vpack group base (32-key groups, x(dt stride 128))
  const int lko = lane*8;

  bf16x8 zero8 = {};
  bf16x8 bq[2][2];
#pragma unroll
  for (int nt = 0; nt < 2; nt++) {
    const bf16_t* qp = qkvb + (size_t)(q0 + nt*16 + ln)*960 + h*40;
    bq[nt][0] = *(const bf16x8*)(qp + qd*8);
    bq[nt][1] = (qd == 0) ? *(const bf16x8*)(qp + 32) : zero8;
  }

  f32x4 zero4 = {0.f,0.f,0.f,0.f};
  f32x4 oacc[3][2];
#pragma unroll
  for (int a = 0; a < 3; a++)
#pragma unroll
    for (int b = 0; b < 2; b++) oacc[a][b] = zero4;

#define FS_LOADK(DST, K0)                                                       \
  {                                                                             \
    const bf16_t* kp_ = kpack + ((size_t)kgbase + ((K0) >> 4)) * 640;           \
    DST[0][0] = *(const bf16x8*)(kp_ + lko);                                    \
    DST[0][1] = (qd == 0) ? *(const bf16x8*)(kp_ + 512 + ln*8) : zero8;         \
    DST[1][0] = *(const bf16x8*)(kp_ + 640 + lko);                              \
    DST[1][1] = (qd == 0) ? *(const bf16x8*)(kp_ + 1152 + ln*8) : zero8;        \
  }

#define FS_LOADV(DST, K0)                                                       \
  {                                                                             \
    _Pragma("unroll")                                                           \
    for (int dt_ = 0; dt_ < 3; dt_++)                                           \
      DST[dt_] = *(const f16x8*)(vpack + ((size_t)vgbase + dt_*128 + ((K0) >> 5)) * 512 + lko); \
  }

#define FS_COMPUTE(KA, VA)                                                      \
  {                                                                             \
    __builtin_amdgcn_s_setprio(1);                                              \
    _Pragma("unroll")                                                           \
    for (int nt = 0; nt < 2; nt++) {                                            \
      f32x4 s0 = __builtin_amdgcn_mfma_f32_16x16x32_bf16(KA[0][0], bq[nt][0], zero4, 0,0,0); \
      s0 = __builtin_amdgcn_mfma_f32_16x16x32_bf16(KA[0][1], bq[nt][1], s0, 0,0,0); \
      f32x4 s1 = __builtin_amdgcn_mfma_f32_16x16x32_bf16(KA[1][0], bq[nt][0], zero4, 0,0,0); \
      s1 = __builtin_amdgcn_mfma_f32_16x16x32_bf16(KA[1][1], bq[nt][1], s1, 0,0,0); \
      uint4 u_;                                                                 \
      u_.x = pkh2(__builtin_amdgcn_exp2f(s0[0]), __builtin_amdgcn_exp2f(s0[1])); \
      u_.y = pkh2(__builtin_amdgcn_exp2f(s0[2]), __builtin_amdgcn_exp2f(s0[3])); \
      u_.z = pkh2(__builtin_amdgcn_exp2f(s1[0]), __builtin_amdgcn_exp2f(s1[1])); \
      u_.w = pkh2(__builtin_amdgcn_exp2f(s1[2]), __builtin_amdgcn_exp2f(s1[3])); \
      f16x8 pb = *(f16x8*)&u_;                                                  \
      _Pragma("unroll")                                                         \
      for (int dt = 0; dt < 3; dt++)                                            \
        oacc[dt][nt] = __builtin_amdgcn_mfma_f32_16x16x32_f16(VA[dt], pb, oacc[dt][nt], 0,0,0); \
    }                                                                           \
    __builtin_amdgcn_s_setprio(0);                                              \
  }

  bf16x8 ka[2][2], kb[2][2];
  f16x8 va[3], vb[3];
  FS_LOADK(ka, 0);
  FS_LOADV(va, 0);
#pragma unroll 1
  for (int it = 0; it < 32; it += 2) {
    const int k0 = it*128;
    FS_LOADK(kb, k0 + 128);
    FS_LOADV(vb, k0 + 128);
    FS_COMPUTE(ka, va);
    FS_LOADK(ka, (it + 2 < 32) ? (k0 + 256) : 0);  // wrap: harmless garbage prefetch
    FS_LOADV(va, (it + 2 < 32) ? (k0 + 256) : 0);
    FS_COMPUTE(kb, vb);
  }
#undef FS_LOADK
#undef FS_LOADV
#undef FS_COMPUTE

  // ---- epilogue: reduce the 4 kh waves in LDS, normalize, write bf16 o1a (32 q-rows) ----
#pragma unroll
  for (int nt = 0; nt < 2; nt++)
#pragma unroll
    for (int dt = 0; dt < 3; dt++)
      *(f32x4*)&Red[((w*2 + nt)*3 + dt)*256 + ln*16 + qd*4] = oacc[dt][nt];
  __syncthreads();
  const int dgrp = tid & 7, lq = (tid >> 3) & 15, ntw = (tid >> 7) & 1;
  float l = Red[((0*2 + ntw)*3 + 2)*256 + lq*16 + 8]
          + Red[((1*2 + ntw)*3 + 2)*256 + lq*16 + 8]
          + Red[((2*2 + ntw)*3 + 2)*256 + lq*16 + 8]
          + Red[((3*2 + ntw)*3 + 2)*256 + lq*16 + 8];
  float inv = 1.f / l;
  bf16_t* obase = o1a + (size_t)(q0 + ntw*16 + lq)*320 + h*40;
#pragma unroll
  for (int i = 0; i < 5; i++) {
    int d = dgrp + i*8;
    int dt = d >> 4, dr = d & 15;
    float o = Red[((0*2 + ntw)*3 + dt)*256 + lq*16 + dr]
            + Red[((1*2 + ntw)*3 + dt)*256 + lq*16 + dr]
            + Red[((2*2 + ntw)*3 + dt)*256 + lq*16 + dr]
            + Red[((3*2 + ntw)*3 + dt)*256 + lq*16 + dr];
    obase[d] = f2b(o * inv);
  }
}

// =========================== cross-attention (setprio around MFMA clusters) ===========================
__global__ __launch_bounds__(256) void attn_cross_kernel(
    const float* __restrict__ q2, const bf16_t* __restrict__ k2h, const bf16_t* __restrict__ k2l,
    const bf16_t* __restrict__ famh, const bf16_t* __restrict__ faml,
    const bf16_t* __restrict__ v2t, const int* __restrict__ use_fca,
    bf16_t* __restrict__ o2)
{
  __shared__ bf16_t SMh[4][16*96];
  __shared__ bf16_t SMl[4][16*96];
  __shared__ bf16_t PAs[4][16*96];
  const int tid = threadIdx.x;
  const int w = tid >> 6, lane = tid & 63;
  const int ln = lane & 15, qd = lane >> 4;
  const int h = blockIdx.x & 7;
  const int q0 = (blockIdx.x >> 3)*64 + w*16;
  const int fca = use_fca[0];
  bf16_t* smh = SMh[w];
  bf16_t* sml = SMl[w];
  bf16_t* pa  = PAs[w];

  {
    bf16x4 z = {};
    int q = lane >> 2, c = 80 + (lane & 3)*4;
    *(bf16x4*)&smh[q*96 + c] = z;
    *(bf16x4*)&sml[q*96 + c] = z;
    *(bf16x4*)&pa [q*96 + c] = z;
  }

  bf16x8 zero8 = {};
  bf16x8 aqh0, aql0, aqh1 = zero8, aql1 = zero8;
  {
    const float* qp = q2 + (size_t)(q0 + ln)*320 + h*40;
    float4 v0 = *(const float4*)(qp + qd*8);
    float4 v1 = *(const float4*)(qp + qd*8 + 4);
    float qv[8] = {v0.x,v0.y,v0.z,v0.w,v1.x,v1.y,v1.z,v1.w};
#pragma unroll
    for (int i = 0; i < 8; i++) {
      bf16_t hh = f2b(qv[i]);
      aqh0[i] = hh; aql0[i] = f2b(qv[i] - b2f(hh));
    }
    if (qd == 0) {
      float4 u0 = *(const float4*)(qp + 32);
      float4 u1 = *(const float4*)(qp + 36);
      float uv[8] = {u0.x,u0.y,u0.z,u0.w,u1.x,u1.y,u1.z,u1.w};
#pragma unroll
      for (int i = 0; i < 8; i++) {
        bf16_t hh = f2b(uv[i]);
        aqh1[i] = hh; aql1[i] = f2b(uv[i] - b2f(hh));
      }
    }
  }

  f32x4 zero4 = {0.f,0.f,0.f,0.f};
  float ss[5][4];
  __builtin_amdgcn_s_setprio(1);
#pragma unroll
  for (int nt = 0; nt < 5; nt++) {
    const bf16_t* kb = k2h + ((size_t)h*96 + nt*16 + ln)*64 + qd*8;
    const bf16_t* kl = k2l + ((size_t)h*96 + nt*16 + ln)*64 + qd*8;
    bf16x8 kh0 = *(const bf16x8*)kb;
    bf16x8 kh1 = *(const bf16x8*)(kb + 32);
    bf16x8 kl0 = *(const bf16x8*)kl;
    bf16x8 kl1 = *(const bf16x8*)(kl + 32);
    f32x4 s;
    s = __builtin_amdgcn_mfma_f32_16x16x32_bf16(aqh0, kl0, zero4, 0, 0, 0);
    s = __builtin_amdgcn_mfma_f32_16x16x32_bf16(aql0, kh0, s, 0, 0, 0);
    s = __builtin_amdgcn_mfma_f32_16x16x32_bf16(aqh0, kh0, s, 0, 0, 0);
    s = __builtin_amdgcn_mfma_f32_16x16x32_bf16(aqh1, kl1, s, 0, 0, 0);
    s = __builtin_amdgcn_mfma_f32_16x16x32_bf16(aql1, kh1, s, 0, 0, 0);
    s = __builtin_amdgcn_mfma_f32_16x16x32_bf16(aqh1, kh1, s, 0, 0, 0);
#pragma unroll
    for (int r = 0; r < 4; r++) {
      float sv = s[r] * ATT_SCALE;
      ss[nt][r] = sv;
      bf16_t hh = f2b(sv);
      smh[(qd*4 + r)*96 + nt*16 + ln] = hh;
      sml[(qd*4 + r)*96 + nt*16 + ln] = f2b(sv - b2f(hh));
    }
  }
  __builtin_amdgcn_s_setprio(0);

  f32x4 facc[5];
#pragma unroll
  for (int nt = 0; nt < 5; nt++) facc[nt] = zero4;
  __builtin_amdgcn_s_setprio(1);
#pragma unroll
  for (int c = 0; c < 3; c++) {
    bf16x8 sah = *(const bf16x8*)&smh[ln*96 + c*32 + qd*8];
    bf16x8 sal = *(const bf16x8*)&sml[ln*96 + c*32 + qd*8];
#pragma unroll
    for (int nt = 0; nt < 5; nt++) {
      bf16x8 fh8 = *(const bf16x8*)(famh + ((size_t)(nt*16 + ln))*96 + c*32 + qd*8);
      bf16x8 fl8 = *(const bf16x8*)(faml + ((size_t)(nt*16 + ln))*96 + c*32 + qd*8);
      facc[nt] = __builtin_amdgcn_mfma_f32_16x16x32_bf16(sah, fl8, facc[nt], 0, 0, 0);
      facc[nt] = __builtin_amdgcn_mfma_f32_16x16x32_bf16(sal, fh8, facc[nt], 0, 0, 0);
      facc[nt] = __builtin_amdgcn_mfma_f32_16x16x32_bf16(sah, fh8, facc[nt], 0, 0, 0);
    }
  }
  __builtin_amdgcn_s_setprio(0);

  float pr[5][4];
  if (fca) {
    float fwv[5][4], fm[4];
#pragma unroll
    for (int nt = 0; nt < 5; nt++)
#pragma unroll
      for (int r = 0; r < 4; r++) fwv[nt][r] = fminf(fabsf(facc[nt][r]), 1.f);
#pragma unroll
    for (int r = 0; r < 4; r++) {
      float m = fmaxf(fmaxf(fwv[0][r], fwv[1][r]), fmaxf(fwv[2][r], fmaxf(fwv[3][r], fwv[4][r])));
#pragma unroll
      for (int o = 8; o; o >>= 1) m = fmaxf(m, __shfl_xor(m, o));
      fm[r] = m;
    }
#pragma unroll
    for (int nt = 0; nt < 5; nt++)
#pragma unroll
      for (int r = 0; r < 4; r++) {
        float lg = ss[nt][r] - ((fwv[nt][r] > 0.6f*(fm[r] + 1e-6f)) ? 0.f : 50.f);
        pr[nt][r] = __builtin_amdgcn_exp2f(lg * LOG2E);
      }
  } else {
#pragma unroll
    for (int nt = 0; nt < 5; nt++)
#pragma unroll
      for (int r = 0; r < 4; r++)
        pr[nt][r] = __builtin_amdgcn_exp2f(ss[nt][r] * LOG2E);
  }
  if (ln >= 13) {
#pragma unroll
    for (int r = 0; r < 4; r++) pr[4][r] = 0.f;
  }
  float l_[4] = {0.f,0.f,0.f,0.f};
#pragma unroll
  for (int nt = 0; nt < 5; nt++)
#pragma unroll
    for (int r = 0; r < 4; r++) {
      l_[r] += pr[nt][r];
      pa[(qd*4 + r)*96 + nt*16 + ln] = f2b(pr[nt][r]);
    }
#pragma unroll
  for (int r = 0; r < 4; r++)
#pragma unroll
    for (int o = 8; o; o >>= 1) l_[r] += __shfl_xor(l_[r], o);

  f32x4 oacc[3];
#pragma unroll
  for (int nt = 0; nt < 3; nt++) oacc[nt] = zero4;
  __builtin_amdgcn_s_setprio(1);
#pragma unroll
  for (int c = 0; c < 3; c++) {
    bf16x8 paf = *(const bf16x8*)&pa[ln*96 + c*32 + qd*8];
#pragma unroll
    for (int nt = 0; nt < 3; nt++) {
      bf16x8 vb = *(const bf16x8*)(v2t + ((size_t)h*48 + nt*16 + ln)*96 + c*32 + qd*8);
      oacc[nt] = __builtin_amdgcn_mfma_f32_16x16x32_bf16(paf, vb, oacc[nt], 0, 0, 0);
    }
  }
  __builtin_amdgcn_s_setprio(0);
  float inv[4];
#pragma unroll
  for (int r = 0; r < 4; r++) inv[r] = 1.f / l_[r];
#pragma unroll
  for (int nt = 0; nt < 3; nt++) {
    int d = nt*16 + ln;
    if (d < 40) {
#pragma unroll
      for (int r = 0; r < 4; r++)
        o2[(size_t)(q0 + qd*4 + r)*320 + h*40 + d] = f2b(oacc[nt][r]*inv[r]);
    }
  }
}

// =========================== bf16 MFMA GEMM 128x64 (gl_lds + swizzle + 2-phase dbuf) ===========================
template<int OUT_BF16>
__global__ __launch_bounds__(256) void gemm_bf16_kernel(
    const bf16_t* __restrict__ A, const bf16_t* __restrict__ Bt,
    const float* __restrict__ bias, const float* __restrict__ resid,
    void* __restrict__ Cout, int M, int N, int K)
{
  __shared__ __align__(16) bf16_t As[2][128][64];
  __shared__ __align__(16) bf16_t Bs[2][64][64];
  const int tid = threadIdx.x;
  const int m0 = blockIdx.x * 128, n0 = blockIdx.y * 64;
  const int w = tid >> 6, lane = tid & 63;
  const int wr = w >> 1, wc = w & 1;
  const int ln = lane & 15, qd = lane >> 4;
  const int lr = lane >> 3, lsw = (lane & 7) ^ lr;   // row-in-wave, swizzled source col8
  f32x4 zero = {0.f, 0.f, 0.f, 0.f};
  f32x4 acc[4][2];
#pragma unroll
  for (int a = 0; a < 4; a++)
#pragma unroll
    for (int b = 0; b < 2; b++) acc[a][b] = zero;

#define GB_STAGE(BI, KK)                                                          \
  {                                                                               \
    char* asb_ = (char*)&As[BI][0][0];                                            \
    char* bsb_ = (char*)&Bs[BI][0][0];                                            \
    _Pragma("unroll")                                                             \
    for (int i = 0; i < 4; i++)                                                   \
      gl_lds16(A + (size_t)(m0 + (i*4 + w)*8 + lr)*K + (KK) + lsw*8, asb_ + (i*4 + w)*1024); \
    _Pragma("unroll")                                                             \
    for (int i = 0; i < 2; i++)                                                   \
      gl_lds16(Bt + (size_t)(n0 + (i*4 + w)*8 + lr)*K + (KK) + lsw*8, bsb_ + (i*4 + w)*1024); \
  }

  const int NT = K >> 6;
  GB_STAGE(0, 0)
  __syncthreads();
  for (int t = 0; t < NT; t++) {
    if (t + 1 < NT) GB_STAGE((t + 1) & 1, (t + 1) * 64)
    const int bi = t & 1;
#pragma unroll
    for (int c = 0; c < 2; c++) {
      const int sa = (((c*4 + qd) ^ (ln & 7))) * 8;
      bf16x8 af[4], bfr[2];
#pragma unroll
      for (int mt = 0; mt < 4; mt++)
        af[mt] = *(const bf16x8*)&As[bi][wr*64 + mt*16 + ln][sa];
#pragma unroll
      for (int nt = 0; nt < 2; nt++)
        bfr[nt] = *(const bf16x8*)&Bs[bi][wc*32 + nt*16 + ln][sa];
#pragma unroll
      for (int mt = 0; mt < 4; mt++)
#pragma unroll
        for (int nt = 0; nt < 2; nt++)
          acc[mt][nt] = __builtin_amdgcn_mfma_f32_16x16x32_bf16(af[mt], bfr[nt], acc[mt][nt], 0, 0, 0);
    }
    __syncthreads();
  }
#undef GB_STAGE
#pragma unroll
  for (int mt = 0; mt < 4; mt++)
#pragma unroll
    for (int nt = 0; nt < 2; nt++)
#pragma unroll
      for (int r = 0; r < 4; r++) {
        int gm = m0 + wr*64 + mt*16 + qd*4 + r;
        int gn = n0 + wc*32 + nt*16 + ln;
        float v = acc[mt][nt][r];
        if (bias)  v += bias[gn];
        if (resid) v += resid[(size_t)gm*N + gn];
        if (OUT_BF16) sto(v, &((bf16_t*)Cout)[(size_t)gm*N + gn]);
        else          sto(v, &((float*)Cout)[(size_t)gm*N + gn]);
      }
}

// =========================== bf16 MFMA GEMM 32x64 (gl_lds + swizzle + 2-phase dbuf) ===========================
template<int OUT_BF16>
__global__ __launch_bounds__(256) void gemm_bf16_32_kernel(
    const bf16_t* __restrict__ A, const bf16_t* __restrict__ Bt,
    const float* __restrict__ bias, const float* __restrict__ resid,
    void* __restrict__ Cout, int M, int N, int K)
{
  __shared__ __align__(16) bf16_t As[2][32][64];
  __shared__ __align__(16) bf16_t Bs[2][64][64];
  const int tid = threadIdx.x;
  const int m0 = blockIdx.x * 32, n0 = blockIdx.y * 64;
  const int w = tid >> 6, lane = tid & 63;
  const int wr = w >> 1, wc = w & 1;
  const int ln = lane & 15, qd = lane >> 4;
  const int lr = lane >> 3, lsw = (lane & 7) ^ lr;
  f32x4 zero = {0.f, 0.f, 0.f, 0.f};
  f32x4 acc[2];
  acc[0] = zero; acc[1] = zero;

#define GB32_STAGE(BI, KK)                                                        \
  {                                                                               \
    char* asb_ = (char*)&As[BI][0][0];                                            \
    char* bsb_ = (char*)&Bs[BI][0][0];                                            \
    gl_lds16(A + (size_t)(m0 + w*8 + lr)*K + (KK) + lsw*8, asb_ + w*1024);        \
    _Pragma("unroll")                                                             \
    for (int i = 0; i < 2; i++)                                                   \
      gl_lds16(Bt + (size_t)(n0 + (i*4 + w)*8 + lr)*K + (KK) + lsw*8, bsb_ + (i*4 + w)*1024); \
  }

  const int NT = K >> 6;
  GB32_STAGE(0, 0)
  __syncthreads();
  for (int t = 0; t < NT; t++) {
    if (t + 1 < NT) GB32_STAGE((t + 1) & 1, (t + 1) * 64)
    const int bi = t & 1;
#pragma unroll
    for (int c = 0; c < 2; c++) {
      const int sa = (((c*4 + qd) ^ (ln & 7))) * 8;
      bf16x8 af = *(const bf16x8*)&As[bi][wr*16 + ln][sa];
#pragma unroll
      for (int nt = 0; nt < 2; nt++) {
        bf16x8 bfr = *(const bf16x8*)&Bs[bi][wc*32 + nt*16 + ln][sa];
        acc[nt] = __builtin_amdgcn_mfma_f32_16x16x32_bf16(af, bfr, acc[nt], 0, 0, 0);
      }
    }
    __syncthreads();
  }
#undef GB32_STAGE
#pragma unroll
  for (int nt = 0; nt < 2; nt++)
#pragma unroll
    for (int r = 0; r < 4; r++) {
      int gm = m0 + wr*16 + qd*4 + r;
      int gn = n0 + wc*32 + nt*16 + ln;
      float v = acc[nt][r];
      if (bias)  v += bias[gn];
      if (resid) v += resid[(size_t)gm*N + gn];
      if (OUT_BF16) sto(v, &((bf16_t*)Cout)[(size_t)gm*N + gn]);
      else          sto(v, &((float*)Cout)[(size_t)gm*N + gn]);
    }
}

// =========================== 3-term bf16 MFMA GEMM (gl_lds + swizzle + 2-phase dbuf) ===========================
__global__ __launch_bounds__(256) void gemm3_32_kernel(
    const bf16_t* __restrict__ Ah, const bf16_t* __restrict__ Al,
    const bf16_t* __restrict__ Bth, const bf16_t* __restrict__ Btl,
    float* __restrict__ C, int M, int N, int K)
{
  __shared__ __align__(16) bf16_t Ash[2][32][64];
  __shared__ __align__(16) bf16_t Asl[2][32][64];
  __shared__ __align__(16) bf16_t Bsh[2][64][64];
  __shared__ __align__(16) bf16_t Bsl[2][64][64];
  const int tid = threadIdx.x;
  const int m0 = blockIdx.x * 32, n0 = blockIdx.y * 64;
  const int w = tid >> 6, lane = tid & 63;
  const int wr = w >> 1, wc = w & 1;
  const int ln = lane & 15, qd = lane >> 4;
  const int lr = lane >> 3, lsw = (lane & 7) ^ lr;
  f32x4 zero = {0.f, 0.f, 0.f, 0.f};
  f32x4 acc[2];
  acc[0] = zero; acc[1] = zero;

#define G3_STAGE(BI, KK)                                                          \
  {                                                                               \
    char* ash_ = (char*)&Ash[BI][0][0];                                           \
    char* asl_ = (char*)&Asl[BI][0][0];                                           \
    char* bsh_ = (char*)&Bsh[BI][0][0];                                           \
    char* bsl_ = (char*)&Bsl[BI][0][0];                                           \
    gl_lds16(Ah + (size_t)(m0 + w*8 + lr)*K + (KK) + lsw*8, ash_ + w*1024);       \
    gl_lds16(Al + (size_t)(m0 + w*8 + lr)*K + (KK) + lsw*8, asl_ + w*1024);       \
    _Pragma("unroll")                                                             \
    for (int i = 0; i < 2; i++) {                                                 \
      gl_lds16(Bth + (size_t)(n0 + (i*4 + w)*8 + lr)*K + (KK) + lsw*8, bsh_ + (i*4 + w)*1024); \
      gl_lds16(Btl + (size_t)(n0 + (i*4 + w)*8 + lr)*K + (KK) + lsw*8, bsl_ + (i*4 + w)*1024); \
    }                                                                             \
  }

  const int NT = K >> 6;
  G3_STAGE(0, 0)
  __syncthreads();
  for (int t = 0; t < NT; t++) {
    if (t + 1 < NT) G3_STAGE((t + 1) & 1, (t + 1) * 64)
    const int bi = t & 1;
#pragma unroll
    for (int c = 0; c < 2; c++) {
      const int sa = (((c*4 + qd) ^ (ln & 7))) * 8;
      bf16x8 afh = *(const bf16x8*)&Ash[bi][wr*16 + ln][sa];
      bf16x8 afl = *(const bf16x8*)&Asl[bi][wr*16 + ln][sa];
#pragma unroll
      for (int nt = 0; nt < 2; nt++) {
        bf16x8 bfh = *(const bf16x8*)&Bsh[bi][wc*32 + nt*16 + ln][sa];
        bf16x8 bfl = *(const bf16x8*)&Bsl[bi][wc*32 + nt*16 + ln][sa];
        acc[nt] = __builtin_amdgcn_mfma_f32_16x16x32_bf16(afh, bfl, acc[nt], 0, 0, 0);
        acc[nt] = __builtin_amdgcn_mfma_f32_16x16x32_bf16(afl, bfh, acc[nt], 0, 0, 0);
        acc[nt] = __builtin_amdgcn_mfma_f32_16x16x32_bf16(afh, bfh, acc[nt], 0, 0, 0);
      }
    }
    __syncthreads();
  }
#undef G3_STAGE
#pragma unroll
  for (int nt = 0; nt < 2; nt++)
#pragma unroll
    for (int r = 0; r < 4; r++) {
      int gm = m0 + wr*16 + qd*4 + r;
      int gn = n0 + wc*32 + nt*16 + ln;
      C[(size_t)gm*N + gn] = acc[nt][r];
    }
}

// =========================== fused FF1 GEMM + GEGLU (gl_lds + swizzle, single-buffered) ===========================
__global__ __launch_bounds__(256) void gemm_geglu_kernel(
    const bf16_t* __restrict__ A, const bf16_t* __restrict__ Bt,
    const float* __restrict__ bias, bf16_t* __restrict__ gg, int K)
{
  __shared__ __align__(16) bf16_t As[128][64];
  __shared__ __align__(16) bf16_t Ba[64][64];
  __shared__ __align__(16) bf16_t Bg[64][64];
  const int tid = threadIdx.x;
  const int m0 = blockIdx.x * 128, n0 = blockIdx.y * 64;
  const int w = tid >> 6, lane = tid & 63;
  const int wr = w >> 1, wc = w & 1;
  const int ln = lane & 15, qd = lane >> 4;
  const int lr = lane >> 3, lsw = (lane & 7) ^ lr;
  char* asb = (char*)&As[0][0];
  char* bab = (char*)&Ba[0][0];
  char* bgb = (char*)&Bg[0][0];
  f32x4 zero = {0.f, 0.f, 0.f, 0.f};
  f32x4 acca[4][2], accg[4][2];
#pragma unroll
  for (int a = 0; a < 4; a++)
#pragma unroll
    for (int b = 0; b < 2; b++) { acca[a][b] = zero; accg[a][b] = zero; }

  for (int k0 = 0; k0 < K; k0 += 64) {
    __syncthreads();
#pragma unroll
    for (int i = 0; i < 4; i++)
      gl_lds16(A + (size_t)(m0 + (i*4 + w)*8 + lr)*K + k0 + lsw*8, asb + (i*4 + w)*1024);
#pragma unroll
    for (int i = 0; i < 2; i++) {
      gl_lds16(Bt + (size_t)(n0 + (i*4 + w)*8 + lr)*K + k0 + lsw*8, bab + (i*4 + w)*1024);
      gl_lds16(Bt + (size_t)(n0 + 1280 + (i*4 + w)*8 + lr)*K + k0 + lsw*8, bgb + (i*4 + w)*1024);
    }
    __syncthreads();
#pragma unroll
    for (int c = 0; c < 2; c++) {
      const int sa = (((c*4 + qd) ^ (ln & 7))) * 8;
      bf16x8 af[4], ba[2], bg[2];
#pragma unroll
      for (int mt = 0; mt < 4; mt++)
        af[mt] = *(const bf16x8*)&As[wr*64 + mt*16 + ln][sa];
#pragma unroll
      for (int nt = 0; nt < 2; nt++) {
        ba[nt] = *(const bf16x8*)&Ba[wc*32 + nt*16 + ln][sa];
        bg[nt] = *(const bf16x8*)&Bg[wc*32 + nt*16 + ln][sa];
      }
#pragma unroll
      for (int mt = 0; mt < 4; mt++)
#pragma unroll
        for (int nt = 0; nt < 2; nt++) {
          acca[mt][nt] = __builtin_amdgcn_mfma_f32_16x16x32_bf16(af[mt], ba[nt], acca[mt][nt], 0, 0, 0);
          accg[mt][nt] = __builtin_amdgcn_mfma_f32_16x16x32_bf16(af[mt], bg[nt], accg[mt][nt], 0, 0, 0);
        }
    }
  }
#pragma unroll
  for (int mt = 0; mt < 4; mt++)
#pragma unroll
    for (int nt = 0; nt < 2; nt++)
#pragma unroll
      for (int r = 0; r < 4; r++) {
        int gm = m0 + wr*64 + mt*16 + qd*4 + r;
        int gn = n0 + wc*32 + nt*16 + ln;
        float va = acca[mt][nt][r] + bias[gn];
        float vg = accg[mt][nt][r] + bias[1280 + gn];
        float ge = 0.5f * vg * (1.f + erff(vg * 0.70710678118654752f));
        gg[(size_t)gm*1280 + gn] = f2b(va * ge);
      }
}

// =========================== launch ===========================
extern "C" void kernel_launch(void* const* d_in, const int* in_sizes, int n_in,
                              void* d_out, int out_size, void* d_ws, size_t ws_size,
                              hipStream_t stream)
{
  const float* x    = (const float*)d_in[0];
  const float* ctx  = (const float*)d_in[1];
  const float* fam  = (const float*)d_in[2];
  const float* g1   = (const float*)d_in[3];
  const float* b1   = (const float*)d_in[4];
  const float* g2   = (const float*)d_in[5];
  const float* b2   = (const float*)d_in[6];
  const float* g3   = (const float*)d_in[7];
  const float* b3   = (const float*)d_in[8];
  const float* Wq1  = (const float*)d_in[9];
  const float* Wk1  = (const float*)d_in[10];
  const float* Wv1  = (const float*)d_in[11];
  const float* Wo1  = (const float*)d_in[12];
  const float* bo1  = (const float*)d_in[13];
  const float* Wq2  = (const float*)d_in[14];
  const float* Wk2  = (const float*)d_in[15];
  const float* Wv2  = (const float*)d_in[16];
  const float* Wo2  = (const float*)d_in[17];
  const float* bo2  = (const float*)d_in[18];
  const float* Wff1 = (const float*)d_in[19];
  const float* bff1 = (const float*)d_in[20];
  const float* Wff2 = (const float*)d_in[21];
  const float* bff2 = (const float*)d_in[22];
  const int*   ufca = (const int*)d_in[23];

  char* ws = (char*)d_ws;
  bf16_t* qkvb = (bf16_t*)(ws + 0);          //  7,864,320  bf16 [4096][960] (Q pre-scaled)
  f16_t*  vpack = (f16_t*)(ws + 7864320);    //  3,145,728  f16 [8][3][128][512] fragment-packed V
  bf16_t* kpack = (bf16_t*)(ws + 11010048);  //  2,621,440  bf16 [8][256][640]
  bf16_t* h1b  = (bf16_t*)(ws + 13631488);   //  2,621,440
  bf16_t* h2hi = (bf16_t*)(ws + 16252928);   //  2,621,440
  bf16_t* h2lo = (bf16_t*)(ws + 18874368);   //  2,621,440
  float*  x2   = (float*)(ws + 21495808);    //  5,242,880
  float*  q2   = (float*)(ws + 26738688);    //  5,242,880
  bf16_t* o1a  = (bf16_t*)(ws + 26738688);   //  2,621,440  bf16 [4096][320] (overlays q2: o1a dead
                                             //             before gemm3 writes q2; flash->wo1 only)
  bf16_t* o2   = (bf16_t*)(ws + 32178688);   //  2,621,440
  float*  x3   = (float*)(ws + 34800128);    //  5,242,880
  bf16_t* h3b  = (bf16_t*)(ws + 40043008);   //  2,621,440
  bf16_t* wqkvt = (bf16_t*)(ws + 42664448);  //    614,400
  bf16_t* wo1t  = (bf16_t*)(ws + 43278848);  //    204,800
  float*  wkv2t = (float*)(ws + 43483648);   //  1,966,080
  bf16_t* wo2t  = (bf16_t*)(ws + 45449728);  //    204,800
  bf16_t* wff1t = (bf16_t*)(ws + 45654528);  //  1,638,400
  bf16_t* wff2t = (bf16_t*)(ws + 47292928);  //    819,200
  bf16_t* wq2th = (bf16_t*)(ws + 48374272);  //    204,800
  bf16_t* wq2tl = (bf16_t*)(ws + 48579072);  //    204,800
  bf16_t* famh  = (bf16_t*)(ws + 48783872);  //     18,432
  bf16_t* faml  = (bf16_t*)(ws + 48802304);  //     18,432
  bf16_t* k2h   = (bf16_t*)(ws + 48820736);  //     98,304
  bf16_t* k2l   = (bf16_t*)(ws + 48919040);  //     98,304
  bf16_t* v2t   = (bf16_t*)(ws + 49017344);  //     73,728  -> end 49,091,072 (k2h..v2t contiguous = zpad)
  bf16_t* gg   = (bf16_t*)(ws + 21495808);   // bf16 [4096][1280] (FF phase; overlays x2,q2)

  float* xout = (float*)d_out;

  // 1: prep + LN1 (merged, independent block ranges)
  prep_ln_kernel<<<1658, 256, 0, stream>>>(Wq1, Wk1, Wv1, Wo1, Wq2, Wk2, Wv2, Wo2, Wff1, Wff2, fam,
                                           wqkvt, wo1t, wkv2t, wo2t, wff1t, wff2t, wq2th, wq2tl,
                                           famh, faml, k2h, x, g1, b1, h1b);
  // --- attn1 (bf16/f16 MFMA flash) ---
  gemm_bf16_kernel<1><<<dim3(32,15), 256, 0, stream>>>(h1b, wqkvt, nullptr, nullptr, qkvb, 4096, 960, 320);
  repack_vt_kernel<<<dim3(64,8), 256, 0, stream>>>(qkvb, vpack, kpack);
  flash_self_kernel<<<1024, 256, 0, stream>>>(qkvb, kpack, vpack, o1a);
  gemm_bf16_32_kernel<0><<<dim3(128,5), 256, 0, stream>>>(o1a, wo1t, bo1, x, x2, 4096, 320, 320);
  // --- attn2 (ln2_split + gemm3_32) ---
  ln2_split_kernel<<<1024, 256, 0, stream>>>(x2, g2, b2, h2hi, h2lo);
  gemm3_32_kernel<<<dim3(128,5), 256, 0, stream>>>(h2hi, h2lo, wq2th, wq2tl, q2, 4096, 320, 320);
  kv2_dot_kernel<<<160, 256, 0, stream>>>(ctx, wkv2t, k2h, k2l, v2t);
  attn_cross_kernel<<<512, 256, 0, stream>>>(q2, k2h, k2l, famh, faml, v2t, ufca, o2);
  gemm_bf16_32_kernel<0><<<dim3(128,5), 256, 0, stream>>>(o2, wo2t, bo2, x2, x3, 4096, 320, 320);
  // --- GEGLU FF (fused FF1+GEGLU) ---
  ln_kernel<bf16_t><<<1024, 256, 0, stream>>>(x3, g3, b3, h3b);
  gemm_geglu_kernel<<<dim3(32,20), 256, 0, stream>>>(h3b, wff1t, bff1, gg, 320);
  gemm_bf16_32_kernel<0><<<dim3(128,5), 256, 0, stream>>>(gg, wff2t, bff2, x3, xout, 4096, 320, 1280);
}